// Round 1
// baseline (421.013 us; speedup 1.0000x reference)
//
#include <hip/hip_runtime.h>
#include <math.h>

#define NB 8
#define NC 16
#define NH 512
#define NW 512
#define NM 8
#define NHID 64
#define NDEPTH 3

// 2*pi/512
#define ANG512 0.01227184630308513f

// ---------------------------------------------------------------------------
// block-wide reduction of 16 floats across 256 threads (4 waves).
// Result left in lds[0..15]. lds must hold >= 64 floats.
// ---------------------------------------------------------------------------
__device__ __forceinline__ void block_reduce16(float* v, float* lds, int tid) {
    #pragma unroll
    for (int off = 32; off > 0; off >>= 1) {
        #pragma unroll
        for (int k = 0; k < 16; ++k) v[k] += __shfl_down(v[k], off);
    }
    const int wave = tid >> 6;
    if ((tid & 63) == 0) {
        #pragma unroll
        for (int k = 0; k < 16; ++k) lds[wave * 16 + k] = v[k];
    }
    __syncthreads();
    if (tid < 16) {
        lds[tid] = lds[tid] + lds[16 + tid] + lds[32 + tid] + lds[48 + tid];
    }
    __syncthreads();
}

// ---------------------------------------------------------------------------
// k_g0: row-DFT of x folded through the affine lift.
// G0[b,c,row,ky] = fc0_w[c]*Xrow[ky] + 512*fc0_b[c]*(ky==0)
// Xrow[ky] = sum_w x[b,0,row,w] * e^{-2pi i ky w/512}
// ---------------------------------------------------------------------------
__global__ __launch_bounds__(256) void k_g0(const float* __restrict__ x,
        const float* __restrict__ fc0_w, const float* __restrict__ fc0_b,
        float* __restrict__ G) {
    __shared__ float red[64];
    const int tid = threadIdx.x;
    const int b = blockIdx.x >> 9;
    const int row = blockIdx.x & 511;
    const float* xr = x + ((size_t)b * NH + row) * NW;

    float p[16];
    #pragma unroll
    for (int k = 0; k < 16; ++k) p[k] = 0.f;

    #pragma unroll
    for (int px = 0; px < 2; ++px) {
        const int w = tid + px * 256;
        const float v = xr[w];
        float s0, c0;
        __sincosf(ANG512 * (float)w, &s0, &c0);
        float tr = 1.f, ti = 0.f;   // e^{-i k theta}
        p[0] += v;
        #pragma unroll
        for (int ky = 1; ky < 8; ++ky) {
            const float nr = tr * c0 + ti * s0;
            const float ni = ti * c0 - tr * s0;
            tr = nr; ti = ni;
            p[ky]     += v * tr;
            p[8 + ky] += v * ti;
        }
    }
    block_reduce16(p, red, tid);
    if (tid < 128) {
        const int c = tid >> 3, ky = tid & 7;
        const float a = fc0_w[c];
        float gr = a * red[ky];
        float gi = a * red[8 + ky];
        if (ky == 0) gr += 512.f * fc0_b[c];
        const size_t idx = ((((size_t)b * NC + c) * NH + row) * NM + ky) * 2;
        G[idx] = gr;
        G[idx + 1] = gi;
    }
}

// ---------------------------------------------------------------------------
// k_B: X_ft[b,i,kx,ky] = (1/(H*W)) * sum_x G[b,i,x,ky] * e^{-2pi i kx x/512}
// grid: (b*16 + i)*8 + kx  (1024 blocks)
// ---------------------------------------------------------------------------
__global__ __launch_bounds__(256) void k_B(const float* __restrict__ G,
                                           float* __restrict__ Xft) {
    __shared__ float red[64];
    const int tid = threadIdx.x;
    const int kx = blockIdx.x & 7;
    const int ci = (blockIdx.x >> 3) & 15;
    const int b = blockIdx.x >> 7;
    const float* Gb = G + ((size_t)b * NC + ci) * NH * (NM * 2);

    float p[16];
    #pragma unroll
    for (int k = 0; k < 16; ++k) p[k] = 0.f;

    #pragma unroll
    for (int px = 0; px < 2; ++px) {
        const int xx = tid + px * 256;
        const float4* g4 = (const float4*)(Gb + (size_t)xx * 16);
        float s0, c0;
        __sincosf(ANG512 * (float)((kx * xx) & 511), &s0, &c0);
        const float tr = c0, ti = -s0;  // e^{-2pi i kx x/512}
        #pragma unroll
        for (int q = 0; q < 4; ++q) {
            const float4 g = g4[q];
            const int ky = q * 2;
            p[ky]         += g.x * tr - g.y * ti;
            p[8 + ky]     += g.x * ti + g.y * tr;
            p[ky + 1]     += g.z * tr - g.w * ti;
            p[8 + ky + 1] += g.z * ti + g.w * tr;
        }
    }
    block_reduce16(p, red, tid);
    if (tid < 8) {
        const size_t o = ((((size_t)b * NC + ci) * NM + kx) * NM + tid) * 2;
        const float inv = 1.f / (512.f * 512.f);
        Xft[o] = red[tid] * inv;
        Xft[o + 1] = red[8 + tid] * inv;
    }
}

// ---------------------------------------------------------------------------
// k_F: F[b,o,kx,ky] = sum_i X[b,i,kx,ky] * (wr + i wi)[i,o,kx,ky]
// grid: b (8 blocks)
// ---------------------------------------------------------------------------
__global__ __launch_bounds__(256) void k_F(const float* __restrict__ Xft,
        const float* __restrict__ wr, const float* __restrict__ wi,
        float* __restrict__ F) {
    const int b = blockIdx.x;
    const int tid = threadIdx.x;
    for (int k = 0; k < 4; ++k) {
        const int idx = tid + k * 256;
        const int o = idx >> 6, kk = idx & 63;  // kk = kx*8 + ky
        float fr = 0.f, fi = 0.f;
        #pragma unroll
        for (int i = 0; i < 16; ++i) {
            const size_t xi = (((size_t)b * NC + i) * 64 + kk) * 2;
            const float xr = Xft[xi], xim = Xft[xi + 1];
            const size_t widx = ((size_t)i * NC + o) * 64 + kk;
            const float wre = wr[widx], wim = wi[widx];
            fr += xr * wre - xim * wim;
            fi += xr * wim + xim * wre;
        }
        const size_t fo = (((size_t)b * NC + o) * 64 + kk) * 2;
        F[fo] = fr;
        F[fo + 1] = fi;
    }
}

// ---------------------------------------------------------------------------
// k_D: one (b,row) per block. Spectral inverse (from F) + 1x1 conv + bias,
// writes h_next to global, and fused row-DFT of h_next -> Gout (next layer).
// LIFT: input is x [B,1,H,W], lifted on the fly (h0 never materialized).
// Non-LIFT may run in place (hin == hout): block only touches its own rows.
// ---------------------------------------------------------------------------
template<bool LIFT>
__global__ __launch_bounds__(256) void k_D(
        const float* __restrict__ hin,
        const float* __restrict__ fc0_w, const float* __restrict__ fc0_b,
        const float* __restrict__ Fm,
        const float* __restrict__ cw, const float* __restrict__ cb,
        float* __restrict__ hout, float* __restrict__ Gout) {
    __shared__ float F_s[2048];      // [o][kx][ky][2]
    __shared__ float U_s[16][16];    // [o][ky*2 + re/im], c_ky folded in
    __shared__ float cw_s[256];      // [o][c]
    __shared__ float cb_s[16];
    __shared__ float hrow[16][513];  // input row; overwritten by h_next in pass 1

    const int tid = threadIdx.x;
    const int b = blockIdx.x >> 9;
    const int row = blockIdx.x & 511;

    // ---- stage weights + load input row ----
    const float* Fb = Fm + (size_t)b * 2048;
    #pragma unroll
    for (int k = 0; k < 8; ++k) F_s[tid + k * 256] = Fb[tid + k * 256];
    cw_s[tid] = cw[tid];
    if (tid < 16) cb_s[tid] = cb[tid];

    if (LIFT) {
        const float* xr = hin + ((size_t)b * NH + row) * NW;
        const float x0 = xr[tid];
        const float x1 = xr[tid + 256];
        #pragma unroll
        for (int c = 0; c < 16; ++c) {
            const float a = fc0_w[c];   // uniform -> scalar loads
            const float bb = fc0_b[c];
            hrow[c][tid] = a * x0 + bb;
            hrow[c][tid + 256] = a * x1 + bb;
        }
    } else {
        #pragma unroll
        for (int c = 0; c < 16; ++c) {
            const float* hr = hin + (((size_t)b * NC + c) * NH + row) * NW;
            hrow[c][tid] = hr[tid];
            hrow[c][tid + 256] = hr[tid + 256];
        }
    }
    __syncthreads();

    // ---- U[o,ky] = c_ky * sum_kx F[o,kx,ky] e^{+2pi i kx row/512} ----
    if (tid < 128) {
        const int o = tid >> 3, ky = tid & 7;
        float s0, c0;
        __sincosf(ANG512 * (float)row, &s0, &c0);
        float tr = 1.f, ti = 0.f;   // e^{+i kx phi}
        float ur = 0.f, ui = 0.f;
        #pragma unroll
        for (int kx = 0; kx < 8; ++kx) {
            const float fr = F_s[(o * 64 + kx * 8 + ky) * 2];
            const float fi = F_s[(o * 64 + kx * 8 + ky) * 2 + 1];
            ur += fr * tr - fi * ti;
            ui += fr * ti + fi * tr;
            const float nr = tr * c0 - ti * s0;
            const float ni = tr * s0 + ti * c0;
            tr = nr; ti = ni;
        }
        const float ck = (ky == 0) ? 1.f : 2.f;
        U_s[o][ky * 2] = ck * ur;
        U_s[o][ky * 2 + 1] = ck * ui;
    }

    // every thread snapshots its two pixels (all channels) before hrow is reused
    float hva[16], hvb[16];
    #pragma unroll
    for (int c = 0; c < 16; ++c) {
        hva[c] = hrow[c][tid];
        hvb[c] = hrow[c][tid + 256];
    }
    __syncthreads();

    // ---- pass 1: h_next = spectral + conv + bias ----
    float cta[8], sta[8];  // e^{+i ky theta_w}, w = tid
    {
        float s0, c0;
        __sincosf(ANG512 * (float)tid, &s0, &c0);
        cta[0] = 1.f; sta[0] = 0.f;
        #pragma unroll
        for (int k = 1; k < 8; ++k) {
            cta[k] = cta[k - 1] * c0 - sta[k - 1] * s0;
            sta[k] = sta[k - 1] * c0 + cta[k - 1] * s0;
        }
    }
    // pixel b = w+256: cos/sin pick up (-1)^ky

    const size_t houtBase = ((size_t)b * NC * NH + row) * NW;
    #pragma unroll
    for (int o = 0; o < 16; ++o) {
        const float4* Uo = (const float4*)(&U_s[o][0]);
        const float4 u0 = Uo[0], u1 = Uo[1], u2 = Uo[2], u3 = Uo[3];
        const float e0 = u0.x * cta[0] - u0.y * sta[0];
        const float o1 = u0.z * cta[1] - u0.w * sta[1];
        const float e2 = u1.x * cta[2] - u1.y * sta[2];
        const float o3 = u1.z * cta[3] - u1.w * sta[3];
        const float e4 = u2.x * cta[4] - u2.y * sta[4];
        const float o5 = u2.z * cta[5] - u2.w * sta[5];
        const float e6 = u3.x * cta[6] - u3.y * sta[6];
        const float o7 = u3.z * cta[7] - u3.w * sta[7];
        const float ya = e0 + o1 + e2 + o3 + e4 + o5 + e6 + o7;
        const float yb = e0 - o1 + e2 - o3 + e4 - o5 + e6 - o7;

        const float4* cwo = (const float4*)(&cw_s[o * 16]);
        const float4 w0 = cwo[0], w1 = cwo[1], w2 = cwo[2], w3 = cwo[3];
        const float la = w0.x * hva[0]  + w0.y * hva[1]  + w0.z * hva[2]  + w0.w * hva[3]
                       + w1.x * hva[4]  + w1.y * hva[5]  + w1.z * hva[6]  + w1.w * hva[7]
                       + w2.x * hva[8]  + w2.y * hva[9]  + w2.z * hva[10] + w2.w * hva[11]
                       + w3.x * hva[12] + w3.y * hva[13] + w3.z * hva[14] + w3.w * hva[15];
        const float lb = w0.x * hvb[0]  + w0.y * hvb[1]  + w0.z * hvb[2]  + w0.w * hvb[3]
                       + w1.x * hvb[4]  + w1.y * hvb[5]  + w1.z * hvb[6]  + w1.w * hvb[7]
                       + w2.x * hvb[8]  + w2.y * hvb[9]  + w2.z * hvb[10] + w2.w * hvb[11]
                       + w3.x * hvb[12] + w3.y * hvb[13] + w3.z * hvb[14] + w3.w * hvb[15];

        const float va = ya + la + cb_s[o];
        const float vb = yb + lb + cb_s[o];
        hrow[o][tid] = va;
        hrow[o][tid + 256] = vb;
        hout[houtBase + (size_t)o * (NH * NW) + tid] = va;
        hout[houtBase + (size_t)o * (NH * NW) + tid + 256] = vb;
    }
    __syncthreads();

    // ---- pass 2: Gout[b,o,row,ky] = sum_w h_next[o][w] e^{-2pi i ky w/512} ----
    // thread -> (o = tid>>4, wg = tid&15); pixels w = wg*16+j paired with w+256.
    {
        const int o2 = tid >> 4, wg = tid & 15;
        float pr[8], pi[8];
        #pragma unroll
        for (int k = 0; k < 8; ++k) { pr[k] = 0.f; pi[k] = 0.f; }
        #pragma unroll
        for (int j = 0; j < 16; ++j) {
            const int w = wg * 16 + j;
            const float v0 = hrow[o2][w];
            const float v1 = hrow[o2][w + 256];
            const float a = v0 + v1, d = v0 - v1;  // twiddle(w+256)=(-1)^ky tw(w)
            float s0, c0;
            __sincosf(ANG512 * (float)w, &s0, &c0);
            float tr = 1.f, ti = 0.f;   // e^{-i ky theta}
            pr[0] += a;
            #pragma unroll
            for (int ky = 1; ky < 8; ++ky) {
                const float nr = tr * c0 + ti * s0;
                const float ni = ti * c0 - tr * s0;
                tr = nr; ti = ni;
                const float v = (ky & 1) ? d : a;
                pr[ky] += v * tr;
                pi[ky] += v * ti;
            }
        }
        // reduce over the 16 wg lanes (sub-groups of 16 within each wave)
        #pragma unroll
        for (int m = 8; m > 0; m >>= 1) {
            #pragma unroll
            for (int k = 0; k < 8; ++k) {
                pr[k] += __shfl_xor(pr[k], m, 16);
                pi[k] += __shfl_xor(pi[k], m, 16);
            }
        }
        if ((tid & 15) == 0) {
            const size_t idx = (((size_t)b * NC + o2) * NH + row) * NM * 2;
            #pragma unroll
            for (int k = 0; k < 8; ++k) {
                Gout[idx + 2 * k] = pr[k];
                Gout[idx + 2 * k + 1] = pi[k];
            }
        }
    }
}

// ---------------------------------------------------------------------------
// k_head: layer 2 (spectral + conv) fused with fc1 -> relu -> fc2.
// h3 never touches HBM; writes d_out directly.
// ---------------------------------------------------------------------------
__global__ __launch_bounds__(256) void k_head(
        const float* __restrict__ hin,
        const float* __restrict__ Fm,
        const float* __restrict__ cw, const float* __restrict__ cb,
        const float* __restrict__ fc1_w, const float* __restrict__ fc1_b,
        const float* __restrict__ fc2_w, const float* __restrict__ fc2_b,
        float* __restrict__ out) {
    __shared__ float F_s[2048];
    __shared__ float U_s[16][16];
    __shared__ float cw_s[256];
    __shared__ float cb_s[16];
    __shared__ float fc1t[64][16];   // transposed: [hd][c]
    __shared__ float fc1b_s[64];
    __shared__ float fc2w_s[64];
    __shared__ float hrow[16][513];

    const int tid = threadIdx.x;
    const int b = blockIdx.x >> 9;
    const int row = blockIdx.x & 511;

    const float* Fb = Fm + (size_t)b * 2048;
    #pragma unroll
    for (int k = 0; k < 8; ++k) F_s[tid + k * 256] = Fb[tid + k * 256];
    cw_s[tid] = cw[tid];
    for (int k = tid; k < 1024; k += 256) fc1t[k & 63][k >> 6] = fc1_w[k];
    if (tid < 64) { fc1b_s[tid] = fc1_b[tid]; fc2w_s[tid] = fc2_w[tid]; }
    if (tid < 16) cb_s[tid] = cb[tid];

    #pragma unroll
    for (int c = 0; c < 16; ++c) {
        const float* hr = hin + (((size_t)b * NC + c) * NH + row) * NW;
        hrow[c][tid] = hr[tid];
        hrow[c][tid + 256] = hr[tid + 256];
    }
    __syncthreads();

    if (tid < 128) {
        const int o = tid >> 3, ky = tid & 7;
        float s0, c0;
        __sincosf(ANG512 * (float)row, &s0, &c0);
        float tr = 1.f, ti = 0.f;
        float ur = 0.f, ui = 0.f;
        #pragma unroll
        for (int kx = 0; kx < 8; ++kx) {
            const float fr = F_s[(o * 64 + kx * 8 + ky) * 2];
            const float fi = F_s[(o * 64 + kx * 8 + ky) * 2 + 1];
            ur += fr * tr - fi * ti;
            ui += fr * ti + fi * tr;
            const float nr = tr * c0 - ti * s0;
            const float ni = tr * s0 + ti * c0;
            tr = nr; ti = ni;
        }
        const float ck = (ky == 0) ? 1.f : 2.f;
        U_s[o][ky * 2] = ck * ur;
        U_s[o][ky * 2 + 1] = ck * ui;
    }
    __syncthreads();

    float cta[8], sta[8];
    {
        float s0, c0;
        __sincosf(ANG512 * (float)tid, &s0, &c0);
        cta[0] = 1.f; sta[0] = 0.f;
        #pragma unroll
        for (int k = 1; k < 8; ++k) {
            cta[k] = cta[k - 1] * c0 - sta[k - 1] * s0;
            sta[k] = sta[k - 1] * c0 + cta[k - 1] * s0;
        }
    }

    float hva[16], hvb[16];
    #pragma unroll
    for (int c = 0; c < 16; ++c) {
        hva[c] = hrow[c][tid];
        hvb[c] = hrow[c][tid + 256];
    }

    float h3a[16], h3b[16];
    #pragma unroll
    for (int o = 0; o < 16; ++o) {
        const float4* Uo = (const float4*)(&U_s[o][0]);
        const float4 u0 = Uo[0], u1 = Uo[1], u2 = Uo[2], u3 = Uo[3];
        const float e0 = u0.x * cta[0] - u0.y * sta[0];
        const float o1 = u0.z * cta[1] - u0.w * sta[1];
        const float e2 = u1.x * cta[2] - u1.y * sta[2];
        const float o3 = u1.z * cta[3] - u1.w * sta[3];
        const float e4 = u2.x * cta[4] - u2.y * sta[4];
        const float o5 = u2.z * cta[5] - u2.w * sta[5];
        const float e6 = u3.x * cta[6] - u3.y * sta[6];
        const float o7 = u3.z * cta[7] - u3.w * sta[7];
        const float ya = e0 + o1 + e2 + o3 + e4 + o5 + e6 + o7;
        const float yb = e0 - o1 + e2 - o3 + e4 - o5 + e6 - o7;

        const float4* cwo = (const float4*)(&cw_s[o * 16]);
        const float4 w0 = cwo[0], w1 = cwo[1], w2 = cwo[2], w3 = cwo[3];
        const float la = w0.x * hva[0]  + w0.y * hva[1]  + w0.z * hva[2]  + w0.w * hva[3]
                       + w1.x * hva[4]  + w1.y * hva[5]  + w1.z * hva[6]  + w1.w * hva[7]
                       + w2.x * hva[8]  + w2.y * hva[9]  + w2.z * hva[10] + w2.w * hva[11]
                       + w3.x * hva[12] + w3.y * hva[13] + w3.z * hva[14] + w3.w * hva[15];
        const float lb = w0.x * hvb[0]  + w0.y * hvb[1]  + w0.z * hvb[2]  + w0.w * hvb[3]
                       + w1.x * hvb[4]  + w1.y * hvb[5]  + w1.z * hvb[6]  + w1.w * hvb[7]
                       + w2.x * hvb[8]  + w2.y * hvb[9]  + w2.z * hvb[10] + w2.w * hvb[11]
                       + w3.x * hvb[12] + w3.y * hvb[13] + w3.z * hvb[14] + w3.w * hvb[15];
        h3a[o] = ya + la + cb_s[o];
        h3b[o] = yb + lb + cb_s[o];
    }

    float acc_a = fc2_b[0];
    float acc_b = acc_a;
    #pragma unroll 8
    for (int hd = 0; hd < 64; ++hd) {
        const float4* r = (const float4*)(&fc1t[hd][0]);
        const float4 r0 = r[0], r1 = r[1], r2 = r[2], r3 = r[3];
        float sa = fc1b_s[hd]
            + r0.x * h3a[0]  + r0.y * h3a[1]  + r0.z * h3a[2]  + r0.w * h3a[3]
            + r1.x * h3a[4]  + r1.y * h3a[5]  + r1.z * h3a[6]  + r1.w * h3a[7]
            + r2.x * h3a[8]  + r2.y * h3a[9]  + r2.z * h3a[10] + r2.w * h3a[11]
            + r3.x * h3a[12] + r3.y * h3a[13] + r3.z * h3a[14] + r3.w * h3a[15];
        float sb = fc1b_s[hd]
            + r0.x * h3b[0]  + r0.y * h3b[1]  + r0.z * h3b[2]  + r0.w * h3b[3]
            + r1.x * h3b[4]  + r1.y * h3b[5]  + r1.z * h3b[6]  + r1.w * h3b[7]
            + r2.x * h3b[8]  + r2.y * h3b[9]  + r2.z * h3b[10] + r2.w * h3b[11]
            + r3.x * h3b[12] + r3.y * h3b[13] + r3.z * h3b[14] + r3.w * h3b[15];
        sa = fmaxf(sa, 0.f);
        sb = fmaxf(sb, 0.f);
        acc_a += sa * fc2w_s[hd];
        acc_b += sb * fc2w_s[hd];
    }
    const size_t ob = ((size_t)b * NH + row) * NW;
    out[ob + tid] = acc_a;
    out[ob + tid + 256] = acc_b;
}

// ---------------------------------------------------------------------------
extern "C" void kernel_launch(void* const* d_in, const int* in_sizes, int n_in,
                              void* d_out, int out_size, void* d_ws, size_t ws_size,
                              hipStream_t stream) {
    const float* x       = (const float*)d_in[0];
    const float* fc0_w   = (const float*)d_in[1];
    const float* fc0_b   = (const float*)d_in[2];
    const float* spec_wr = (const float*)d_in[3];
    const float* spec_wi = (const float*)d_in[4];
    const float* conv_w  = (const float*)d_in[5];
    const float* conv_b  = (const float*)d_in[6];
    const float* fc1_w   = (const float*)d_in[7];
    const float* fc1_b   = (const float*)d_in[8];
    const float* fc2_w   = (const float*)d_in[9];
    const float* fc2_b   = (const float*)d_in[10];
    float* out = (float*)d_out;

    char* ws = (char*)d_ws;
    float* hbuf = (float*)ws;                                   // 134,217,728 B
    size_t off = (size_t)NB * NC * NH * NW * sizeof(float);
    float* G = (float*)(ws + off);                              // 4,194,304 B
    off += (size_t)NB * NC * NH * NM * 2 * sizeof(float);
    float* Xft = (float*)(ws + off);                            // 65,536 B
    off += (size_t)NB * NC * NM * NM * 2 * sizeof(float);
    float* F = (float*)(ws + off);                              // 65,536 B

    k_g0<<<NB * NH, 256, 0, stream>>>(x, fc0_w, fc0_b, G);
    for (int d = 0; d < NDEPTH; ++d) {
        k_B<<<NB * NC * NM, 256, 0, stream>>>(G, Xft);
        k_F<<<NB, 256, 0, stream>>>(Xft, spec_wr + (size_t)d * NC * NC * NM * NM,
                                    spec_wi + (size_t)d * NC * NC * NM * NM, F);
        const float* cwd = conv_w + (size_t)d * NC * NC;
        const float* cbd = conv_b + (size_t)d * NC;
        if (d == 0) {
            k_D<true><<<NB * NH, 256, 0, stream>>>(x, fc0_w, fc0_b, F, cwd, cbd, hbuf, G);
        } else if (d == 1) {
            // in place: each block reads & writes only its own (b,row) rows
            k_D<false><<<NB * NH, 256, 0, stream>>>(hbuf, nullptr, nullptr, F, cwd, cbd, hbuf, G);
        } else {
            k_head<<<NB * NH, 256, 0, stream>>>(hbuf, F, cwd, cbd,
                                                fc1_w, fc1_b, fc2_w, fc2_b, out);
        }
    }
}

// Round 2
// 353.765 us; speedup vs baseline: 1.1901x; 1.1901x over previous
//
#include <hip/hip_runtime.h>
#include <math.h>

#define NB 8
#define NC 16
#define NH 512
#define NW 512
#define NM 8
#define NHID 64
#define NDEPTH 3

// 2*pi/512
#define ANG512 0.01227184630308513f

// ---------------------------------------------------------------------------
// k_tw: exact twiddle table. twd[(w*8+k)*2 + {0,1}] = cos/sin(ANG*w*k), angle
// reduced mod 512 so per-entry accuracy is full fp32 (no recurrence drift).
// ---------------------------------------------------------------------------
__global__ __launch_bounds__(256) void k_tw(float* __restrict__ twd) {
    const int idx = blockIdx.x * 256 + threadIdx.x;   // 0..4095 = w*8+k
    const int w = idx >> 3, k = idx & 7;
    const float ang = ANG512 * (float)((w * k) & 511);
    twd[idx * 2]     = cosf(ang);
    twd[idx * 2 + 1] = sinf(ang);
}

// ---------------------------------------------------------------------------
// block-wide reduction of 16 floats across 256 threads (4 waves).
// Result left in lds[0..15].
// ---------------------------------------------------------------------------
__device__ __forceinline__ void block_reduce16(float* v, float* lds, int tid) {
    #pragma unroll
    for (int off = 32; off > 0; off >>= 1) {
        #pragma unroll
        for (int k = 0; k < 16; ++k) v[k] += __shfl_down(v[k], off);
    }
    const int wave = tid >> 6;
    if ((tid & 63) == 0) {
        #pragma unroll
        for (int k = 0; k < 16; ++k) lds[wave * 16 + k] = v[k];
    }
    __syncthreads();
    if (tid < 16) {
        lds[tid] = lds[tid] + lds[16 + tid] + lds[32 + tid] + lds[48 + tid];
    }
    __syncthreads();
}

// ---------------------------------------------------------------------------
// k_g0: row-DFT of x folded through the affine lift.
// G0[b,c,row,ky] = fc0_w[c]*Xrow[ky] + 512*fc0_b[c]*(ky==0)
// ---------------------------------------------------------------------------
__global__ __launch_bounds__(256) void k_g0(const float* __restrict__ x,
        const float* __restrict__ fc0_w, const float* __restrict__ fc0_b,
        const float* __restrict__ twd, float* __restrict__ G) {
    __shared__ float red[64];
    const int tid = threadIdx.x;
    const int b = blockIdx.x >> 9;
    const int row = blockIdx.x & 511;
    const float* xr = x + ((size_t)b * NH + row) * NW;

    float p[16];
    #pragma unroll
    for (int k = 0; k < 16; ++k) p[k] = 0.f;

    #pragma unroll
    for (int px = 0; px < 2; ++px) {
        const int w = tid + px * 256;
        const float v = xr[w];
        const float4* q = (const float4*)(twd + (size_t)w * 16);
        const float4 q0 = q[0], q1 = q[1], q2 = q[2], q3 = q[3];
        // e^{-i ky theta}: (cos, -sin)
        p[0] += v;
        p[1] = fmaf(v, q0.z, p[1]);  p[9]  = fmaf(-v, q0.w, p[9]);
        p[2] = fmaf(v, q1.x, p[2]);  p[10] = fmaf(-v, q1.y, p[10]);
        p[3] = fmaf(v, q1.z, p[3]);  p[11] = fmaf(-v, q1.w, p[11]);
        p[4] = fmaf(v, q2.x, p[4]);  p[12] = fmaf(-v, q2.y, p[12]);
        p[5] = fmaf(v, q2.z, p[5]);  p[13] = fmaf(-v, q2.w, p[13]);
        p[6] = fmaf(v, q3.x, p[6]);  p[14] = fmaf(-v, q3.y, p[14]);
        p[7] = fmaf(v, q3.z, p[7]);  p[15] = fmaf(-v, q3.w, p[15]);
    }
    block_reduce16(p, red, tid);
    if (tid < 128) {
        const int c = tid >> 3, ky = tid & 7;
        const float a = fc0_w[c];
        float gr = a * red[ky];
        float gi = a * red[8 + ky];
        if (ky == 0) gr += 512.f * fc0_b[c];
        const size_t idx = ((((size_t)b * NC + c) * NH + row) * NM + ky) * 2;
        G[idx] = gr;
        G[idx + 1] = gi;
    }
}

// ---------------------------------------------------------------------------
// k_B: X_ft[b,i,kx,ky] = (1/(H*W)) * sum_x G[b,i,x,ky] * e^{-2pi i kx x/512}
// ---------------------------------------------------------------------------
__global__ __launch_bounds__(256) void k_B(const float* __restrict__ G,
        const float* __restrict__ twd, float* __restrict__ Xft) {
    __shared__ float red[64];
    const int tid = threadIdx.x;
    const int kx = blockIdx.x & 7;
    const int ci = (blockIdx.x >> 3) & 15;
    const int b = blockIdx.x >> 7;
    const float* Gb = G + ((size_t)b * NC + ci) * NH * (NM * 2);

    float p[16];
    #pragma unroll
    for (int k = 0; k < 16; ++k) p[k] = 0.f;

    #pragma unroll
    for (int px = 0; px < 2; ++px) {
        const int xx = tid + px * 256;
        const float4* g4 = (const float4*)(Gb + (size_t)xx * 16);
        const float2 t = *(const float2*)(twd + (size_t)(((kx * xx) & 511) * 8 + 1) * 2);
        const float tr = t.x, ti = -t.y;   // e^{-2pi i kx x/512}
        #pragma unroll
        for (int q = 0; q < 4; ++q) {
            const float4 g = g4[q];
            const int ky = q * 2;
            p[ky]         += g.x * tr - g.y * ti;
            p[8 + ky]     += g.x * ti + g.y * tr;
            p[ky + 1]     += g.z * tr - g.w * ti;
            p[8 + ky + 1] += g.z * ti + g.w * tr;
        }
    }
    block_reduce16(p, red, tid);
    if (tid < 8) {
        const size_t o = ((((size_t)b * NC + ci) * NM + kx) * NM + tid) * 2;
        const float inv = 1.f / (512.f * 512.f);
        Xft[o] = red[tid] * inv;
        Xft[o + 1] = red[8 + tid] * inv;
    }
}

// ---------------------------------------------------------------------------
// k_F: F[b,o,kx,ky] = sum_i X[b,i,kx,ky] * (wr + i wi)[i,o,kx,ky]
// ---------------------------------------------------------------------------
__global__ __launch_bounds__(256) void k_F(const float* __restrict__ Xft,
        const float* __restrict__ wr, const float* __restrict__ wi,
        float* __restrict__ F) {
    const int b = blockIdx.x;
    const int tid = threadIdx.x;
    for (int k = 0; k < 4; ++k) {
        const int idx = tid + k * 256;
        const int o = idx >> 6, kk = idx & 63;  // kk = kx*8 + ky
        float fr = 0.f, fi = 0.f;
        #pragma unroll
        for (int i = 0; i < 16; ++i) {
            const size_t xi = (((size_t)b * NC + i) * 64 + kk) * 2;
            const float xr = Xft[xi], xim = Xft[xi + 1];
            const size_t widx = ((size_t)i * NC + o) * 64 + kk;
            const float wre = wr[widx], wim = wi[widx];
            fr += xr * wre - xim * wim;
            fi += xr * wim + xim * wre;
        }
        const size_t fo = (((size_t)b * NC + o) * 64 + kk) * 2;
        F[fo] = fr;
        F[fo + 1] = fi;
    }
}

// ---------------------------------------------------------------------------
// k_D: one (b,row) per block. Spectral inverse + 1x1 conv + bias; writes
// h_next to global and fused row-DFT of h_next -> Gout.
// No input LDS staging: h/x loaded straight into registers; weights read at
// block-uniform indices from global (-> s_load, SGPR operands).
// ---------------------------------------------------------------------------
template<bool LIFT>
__global__ __launch_bounds__(256) void k_D(
        const float* __restrict__ hin,
        const float* __restrict__ fc0_w, const float* __restrict__ fc0_b,
        const float* __restrict__ Fm,
        const float* __restrict__ cw, const float* __restrict__ cb,
        const float* __restrict__ twd,
        float* __restrict__ hout, float* __restrict__ Gout) {
    __shared__ float U_s[16][16];     // [o][ky*2 + re/im], c_ky folded in
    __shared__ float hrow[16][520];   // h_next; stride 520 -> pass2 reads 2-way (free)

    const int tid = threadIdx.x;
    const int b = blockIdx.x >> 9;
    const int row = blockIdx.x & 511;

    // ---- U[o,ky] = c_ky * sum_kx F[o,kx,ky] e^{+2pi i kx row/512} ----
    if (tid < 128) {
        const int o = tid >> 3, ky = tid & 7;
        const float* Fb = Fm + (size_t)b * 2048;
        float ur = 0.f, ui = 0.f;
        #pragma unroll
        for (int kx = 0; kx < 8; ++kx) {
            const float tc = twd[(row * 8 + kx) * 2];       // uniform -> s_load
            const float ts = twd[(row * 8 + kx) * 2 + 1];
            const float fr = Fb[(o * 64 + kx * 8 + ky) * 2];
            const float fi = Fb[(o * 64 + kx * 8 + ky) * 2 + 1];
            ur += fr * tc - fi * ts;
            ui += fr * ts + fi * tc;
        }
        const float ck = (ky == 0) ? 1.f : 2.f;
        U_s[o][ky * 2] = ck * ur;
        U_s[o][ky * 2 + 1] = ck * ui;
    }

    // ---- load own 2 pixels, all 16 channels, straight to registers ----
    float hva[16], hvb[16];
    if (LIFT) {
        const float* xr = hin + ((size_t)b * NH + row) * NW;
        const float x0 = xr[tid], x1 = xr[tid + 256];
        #pragma unroll
        for (int c = 0; c < 16; ++c) {
            hva[c] = fmaf(fc0_w[c], x0, fc0_b[c]);
            hvb[c] = fmaf(fc0_w[c], x1, fc0_b[c]);
        }
    } else {
        #pragma unroll
        for (int c = 0; c < 16; ++c) {
            const float* hr = hin + (((size_t)b * NC + c) * NH + row) * NW;
            hva[c] = hr[tid];
            hvb[c] = hr[tid + 256];
        }
    }

    // ---- per-pixel twiddles e^{+i ky theta_w}, w = tid, from table ----
    float cta[8], sta[8];
    {
        const float4* q = (const float4*)(twd + (size_t)tid * 16);
        const float4 q0 = q[0], q1 = q[1], q2 = q[2], q3 = q[3];
        cta[0] = q0.x; sta[0] = q0.y; cta[1] = q0.z; sta[1] = q0.w;
        cta[2] = q1.x; sta[2] = q1.y; cta[3] = q1.z; sta[3] = q1.w;
        cta[4] = q2.x; sta[4] = q2.y; cta[5] = q2.z; sta[5] = q2.w;
        cta[6] = q3.x; sta[6] = q3.y; cta[7] = q3.z; sta[7] = q3.w;
    }
    __syncthreads();

    // ---- pass 1: h_next = spectral + conv + bias (pixel w+256 via parity) ----
    const size_t houtBase = ((size_t)b * NC * NH + row) * NW;
    #pragma unroll
    for (int o = 0; o < 16; ++o) {
        const float4* Uo = (const float4*)(&U_s[o][0]);
        const float4 u0 = Uo[0], u1 = Uo[1], u2 = Uo[2], u3 = Uo[3];
        const float e0 = u0.x * cta[0] - u0.y * sta[0];
        const float o1 = u0.z * cta[1] - u0.w * sta[1];
        const float e2 = u1.x * cta[2] - u1.y * sta[2];
        const float o3 = u1.z * cta[3] - u1.w * sta[3];
        const float e4 = u2.x * cta[4] - u2.y * sta[4];
        const float o5 = u2.z * cta[5] - u2.w * sta[5];
        const float e6 = u3.x * cta[6] - u3.y * sta[6];
        const float o7 = u3.z * cta[7] - u3.w * sta[7];
        const float ya = e0 + o1 + e2 + o3 + e4 + o5 + e6 + o7;
        const float yb = e0 - o1 + e2 - o3 + e4 - o5 + e6 - o7;

        float la = cb[o], lb = cb[o];                 // uniform -> s_load
        #pragma unroll
        for (int c = 0; c < 16; ++c) {
            const float wv = cw[o * 16 + c];          // uniform -> s_load
            la = fmaf(wv, hva[c], la);
            lb = fmaf(wv, hvb[c], lb);
        }
        const float va = ya + la;
        const float vb = yb + lb;
        hrow[o][tid] = va;
        hrow[o][tid + 256] = vb;
        hout[houtBase + (size_t)o * (NH * NW) + tid] = va;
        hout[houtBase + (size_t)o * (NH * NW) + tid + 256] = vb;
    }
    __syncthreads();

    // ---- pass 2: Gout[b,o,row,ky] = sum_w h_next[o][w] e^{-2pi i ky w/512} ----
    // thread (o2 = tid>>4, wg = tid&15); w-set = wg + 16j paired with w+256.
    // Chebyshev: c_k = 2c1*c_{k-1} - c_{k-2} (1 FMA/step, no sincos).
    {
        const int o2 = tid >> 4, wg = tid & 15;
        float pr[8], pi[8];
        #pragma unroll
        for (int k = 0; k < 8; ++k) { pr[k] = 0.f; pi[k] = 0.f; }
        #pragma unroll
        for (int j = 0; j < 16; ++j) {
            const int w = wg + 16 * j;            // < 256
            const float v0 = hrow[o2][w];
            const float v1 = hrow[o2][w + 256];
            const float a = v0 + v1, d = v0 - v1;
            const float2 t1 = *(const float2*)(twd + (size_t)(w * 8 + 1) * 2);
            const float c1 = t1.x, s1 = t1.y;
            const float c2k = 2.f * c1;
            pr[0] += a;
            pr[1] = fmaf(d, c1, pr[1]);
            pi[1] = fmaf(-d, s1, pi[1]);
            float ckm = 1.f, skm = 0.f, ck = c1, sk = s1;
            #pragma unroll
            for (int k = 2; k < 8; ++k) {
                const float cn = fmaf(c2k, ck, -ckm);
                const float sn = fmaf(c2k, sk, -skm);
                ckm = ck; skm = sk; ck = cn; sk = sn;
                const float v = (k & 1) ? d : a;
                pr[k] = fmaf(v, ck, pr[k]);
                pi[k] = fmaf(-v, sk, pi[k]);
            }
        }
        #pragma unroll
        for (int m = 8; m > 0; m >>= 1) {
            #pragma unroll
            for (int k = 0; k < 8; ++k) {
                pr[k] += __shfl_xor(pr[k], m, 16);
                pi[k] += __shfl_xor(pi[k], m, 16);
            }
        }
        if (wg == 0) {
            float* gp = Gout + (((size_t)b * NC + o2) * NH + row) * (NM * 2);
            #pragma unroll
            for (int k = 0; k < 8; ++k) {
                gp[2 * k] = pr[k];
                gp[2 * k + 1] = pi[k];
            }
        }
    }
}

// ---------------------------------------------------------------------------
// k_head: layer 2 (spectral + conv) fused with fc1 -> relu -> fc2.
// LDS = U_s only; fc1/fc2 weights via uniform global reads (s_load).
// ---------------------------------------------------------------------------
__global__ __launch_bounds__(256) void k_head(
        const float* __restrict__ hin,
        const float* __restrict__ Fm,
        const float* __restrict__ cw, const float* __restrict__ cb,
        const float* __restrict__ fc1_w, const float* __restrict__ fc1_b,
        const float* __restrict__ fc2_w, const float* __restrict__ fc2_b,
        const float* __restrict__ twd,
        float* __restrict__ out) {
    __shared__ float U_s[16][16];

    const int tid = threadIdx.x;
    const int b = blockIdx.x >> 9;
    const int row = blockIdx.x & 511;

    if (tid < 128) {
        const int o = tid >> 3, ky = tid & 7;
        const float* Fb = Fm + (size_t)b * 2048;
        float ur = 0.f, ui = 0.f;
        #pragma unroll
        for (int kx = 0; kx < 8; ++kx) {
            const float tc = twd[(row * 8 + kx) * 2];
            const float ts = twd[(row * 8 + kx) * 2 + 1];
            const float fr = Fb[(o * 64 + kx * 8 + ky) * 2];
            const float fi = Fb[(o * 64 + kx * 8 + ky) * 2 + 1];
            ur += fr * tc - fi * ts;
            ui += fr * ts + fi * tc;
        }
        const float ck = (ky == 0) ? 1.f : 2.f;
        U_s[o][ky * 2] = ck * ur;
        U_s[o][ky * 2 + 1] = ck * ui;
    }

    float hva[16], hvb[16];
    #pragma unroll
    for (int c = 0; c < 16; ++c) {
        const float* hr = hin + (((size_t)b * NC + c) * NH + row) * NW;
        hva[c] = hr[tid];
        hvb[c] = hr[tid + 256];
    }

    float cta[8], sta[8];
    {
        const float4* q = (const float4*)(twd + (size_t)tid * 16);
        const float4 q0 = q[0], q1 = q[1], q2 = q[2], q3 = q[3];
        cta[0] = q0.x; sta[0] = q0.y; cta[1] = q0.z; sta[1] = q0.w;
        cta[2] = q1.x; sta[2] = q1.y; cta[3] = q1.z; sta[3] = q1.w;
        cta[4] = q2.x; sta[4] = q2.y; cta[5] = q2.z; sta[5] = q2.w;
        cta[6] = q3.x; sta[6] = q3.y; cta[7] = q3.z; sta[7] = q3.w;
    }
    __syncthreads();

    float h3a[16], h3b[16];
    #pragma unroll
    for (int o = 0; o < 16; ++o) {
        const float4* Uo = (const float4*)(&U_s[o][0]);
        const float4 u0 = Uo[0], u1 = Uo[1], u2 = Uo[2], u3 = Uo[3];
        const float e0 = u0.x * cta[0] - u0.y * sta[0];
        const float o1 = u0.z * cta[1] - u0.w * sta[1];
        const float e2 = u1.x * cta[2] - u1.y * sta[2];
        const float o3 = u1.z * cta[3] - u1.w * sta[3];
        const float e4 = u2.x * cta[4] - u2.y * sta[4];
        const float o5 = u2.z * cta[5] - u2.w * sta[5];
        const float e6 = u3.x * cta[6] - u3.y * sta[6];
        const float o7 = u3.z * cta[7] - u3.w * sta[7];
        const float ya = e0 + o1 + e2 + o3 + e4 + o5 + e6 + o7;
        const float yb = e0 - o1 + e2 - o3 + e4 - o5 + e6 - o7;

        float la = cb[o], lb = cb[o];
        #pragma unroll
        for (int c = 0; c < 16; ++c) {
            const float wv = cw[o * 16 + c];
            la = fmaf(wv, hva[c], la);
            lb = fmaf(wv, hvb[c], lb);
        }
        h3a[o] = ya + la;
        h3b[o] = yb + lb;
    }

    float acc_a = fc2_b[0];
    float acc_b = acc_a;
    #pragma unroll 4
    for (int hd = 0; hd < 64; ++hd) {
        float sa = fc1_b[hd], sb = fc1_b[hd];      // uniform -> s_load
        #pragma unroll
        for (int c = 0; c < 16; ++c) {
            const float wv = fc1_w[c * 64 + hd];   // uniform -> s_load
            sa = fmaf(wv, h3a[c], sa);
            sb = fmaf(wv, h3b[c], sb);
        }
        sa = fmaxf(sa, 0.f);
        sb = fmaxf(sb, 0.f);
        const float w2 = fc2_w[hd];
        acc_a = fmaf(sa, w2, acc_a);
        acc_b = fmaf(sb, w2, acc_b);
    }
    const size_t ob = ((size_t)b * NH + row) * NW;
    out[ob + tid] = acc_a;
    out[ob + tid + 256] = acc_b;
}

// ---------------------------------------------------------------------------
extern "C" void kernel_launch(void* const* d_in, const int* in_sizes, int n_in,
                              void* d_out, int out_size, void* d_ws, size_t ws_size,
                              hipStream_t stream) {
    const float* x       = (const float*)d_in[0];
    const float* fc0_w   = (const float*)d_in[1];
    const float* fc0_b   = (const float*)d_in[2];
    const float* spec_wr = (const float*)d_in[3];
    const float* spec_wi = (const float*)d_in[4];
    const float* conv_w  = (const float*)d_in[5];
    const float* conv_b  = (const float*)d_in[6];
    const float* fc1_w   = (const float*)d_in[7];
    const float* fc1_b   = (const float*)d_in[8];
    const float* fc2_w   = (const float*)d_in[9];
    const float* fc2_b   = (const float*)d_in[10];
    float* out = (float*)d_out;

    char* ws = (char*)d_ws;
    float* hbuf = (float*)ws;                                   // 134,217,728 B
    size_t off = (size_t)NB * NC * NH * NW * sizeof(float);
    float* G = (float*)(ws + off);                              // 4,194,304 B
    off += (size_t)NB * NC * NH * NM * 2 * sizeof(float);
    float* Xft = (float*)(ws + off);                            // 65,536 B
    off += (size_t)NB * NC * NM * NM * 2 * sizeof(float);
    float* F = (float*)(ws + off);                              // 65,536 B
    off += (size_t)NB * NC * NM * NM * 2 * sizeof(float);
    float* twd = (float*)(ws + off);                            // 32,768 B

    k_tw<<<16, 256, 0, stream>>>(twd);
    k_g0<<<NB * NH, 256, 0, stream>>>(x, fc0_w, fc0_b, twd, G);
    for (int d = 0; d < NDEPTH; ++d) {
        k_B<<<NB * NC * NM, 256, 0, stream>>>(G, twd, Xft);
        k_F<<<NB, 256, 0, stream>>>(Xft, spec_wr + (size_t)d * NC * NC * NM * NM,
                                    spec_wi + (size_t)d * NC * NC * NM * NM, F);
        const float* cwd = conv_w + (size_t)d * NC * NC;
        const float* cbd = conv_b + (size_t)d * NC;
        if (d == 0) {
            k_D<true><<<NB * NH, 256, 0, stream>>>(x, fc0_w, fc0_b, F, cwd, cbd, twd, hbuf, G);
        } else if (d == 1) {
            // in place: each thread writes only pixels it already read
            k_D<false><<<NB * NH, 256, 0, stream>>>(hbuf, nullptr, nullptr, F, cwd, cbd, twd, hbuf, G);
        } else {
            k_head<<<NB * NH, 256, 0, stream>>>(hbuf, F, cwd, cbd,
                                                fc1_w, fc1_b, fc2_w, fc2_b, twd, out);
        }
    }
}

// Round 3
// 262.308 us; speedup vs baseline: 1.6050x; 1.3487x over previous
//
#include <hip/hip_runtime.h>
#include <math.h>

#define NB 8
#define NC 16
#define NH 512
#define NW 512
#define NM 8
#define NHID 64
#define NDEPTH 3

// 2*pi/512
#define ANG512 0.01227184630308513f

// ---------------------------------------------------------------------------
// k_tw: exact twiddle table. twd[(w*8+k)*2 + {0,1}] = cos/sin(ANG*w*k), angle
// reduced mod 512 so per-entry accuracy is full fp32.
// ---------------------------------------------------------------------------
__global__ __launch_bounds__(256) void k_tw(float* __restrict__ twd) {
    const int idx = blockIdx.x * 256 + threadIdx.x;   // 0..4095 = w*8+k
    const int w = idx >> 3, k = idx & 7;
    const float ang = ANG512 * (float)((w * k) & 511);
    twd[idx * 2]     = cosf(ang);
    twd[idx * 2 + 1] = sinf(ang);
}

// ---------------------------------------------------------------------------
// k_prep: composite conv-chain matrices.
// P0 = C2*C1;  dvec = P0*C0*fc0_w;  evec = P0*(C0*fc0_b + cb0) + C2*cb1 + cb2
// ---------------------------------------------------------------------------
__global__ __launch_bounds__(256) void k_prep(
        const float* __restrict__ conv_w, const float* __restrict__ conv_b,
        const float* __restrict__ fc0_w, const float* __restrict__ fc0_b,
        float* __restrict__ P0, float* __restrict__ dvec, float* __restrict__ evec) {
    __shared__ float P_s[256];
    __shared__ float u_s[16];   // C0*fc0_w
    __shared__ float v_s[16];   // C0*fc0_b
    const int t = threadIdx.x;
    const float* C0 = conv_w;
    const float* C1 = conv_w + 256;
    const float* C2 = conv_w + 512;
    {
        const int o = t >> 4, c = t & 15;
        float s = 0.f;
        for (int k = 0; k < 16; ++k) s += C2[o * 16 + k] * C1[k * 16 + c];
        P_s[t] = s;
        P0[t] = s;
    }
    if (t < 16) {
        float s = 0.f, sb = 0.f;
        for (int c = 0; c < 16; ++c) {
            s  += C0[t * 16 + c] * fc0_w[c];
            sb += C0[t * 16 + c] * fc0_b[c];
        }
        u_s[t] = s;
        v_s[t] = sb;
    }
    __syncthreads();
    if (t < 16) {
        float dv = 0.f, ev = conv_b[32 + t];   // cb2[t]
        for (int k = 0; k < 16; ++k) {
            dv += P_s[t * 16 + k] * u_s[k];
            ev += P_s[t * 16 + k] * (v_s[k] + conv_b[k]);      // + P0*(C0*b0f + cb0)
            ev += C2[t * 16 + k] * conv_b[16 + k];             // + C2*cb1
        }
        dvec[t] = dv;
        evec[t] = ev;
    }
}

// ---------------------------------------------------------------------------
// block-wide reduction of 16 floats across 256 threads (4 waves).
// ---------------------------------------------------------------------------
__device__ __forceinline__ void block_reduce16(float* v, float* lds, int tid) {
    #pragma unroll
    for (int off = 32; off > 0; off >>= 1) {
        #pragma unroll
        for (int k = 0; k < 16; ++k) v[k] += __shfl_down(v[k], off);
    }
    const int wave = tid >> 6;
    if ((tid & 63) == 0) {
        #pragma unroll
        for (int k = 0; k < 16; ++k) lds[wave * 16 + k] = v[k];
    }
    __syncthreads();
    if (tid < 16) {
        lds[tid] = lds[tid] + lds[16 + tid] + lds[32 + tid] + lds[48 + tid];
    }
    __syncthreads();
}

// ---------------------------------------------------------------------------
// k_g0: row-DFT of x folded through the affine lift.
// G0[b,c,row,ky] = fc0_w[c]*Xrow[ky] + 512*fc0_b[c]*(ky==0)
// ---------------------------------------------------------------------------
__global__ __launch_bounds__(256) void k_g0(const float* __restrict__ x,
        const float* __restrict__ fc0_w, const float* __restrict__ fc0_b,
        const float* __restrict__ twd, float* __restrict__ G) {
    __shared__ float red[64];
    const int tid = threadIdx.x;
    const int b = blockIdx.x >> 9;
    const int row = blockIdx.x & 511;
    const float* xr = x + ((size_t)b * NH + row) * NW;

    float p[16];
    #pragma unroll
    for (int k = 0; k < 16; ++k) p[k] = 0.f;

    #pragma unroll
    for (int px = 0; px < 2; ++px) {
        const int w = tid + px * 256;
        const float v = xr[w];
        const float4* q = (const float4*)(twd + (size_t)w * 16);
        const float4 q0 = q[0], q1 = q[1], q2 = q[2], q3 = q[3];
        p[0] += v;
        p[1] = fmaf(v, q0.z, p[1]);  p[9]  = fmaf(-v, q0.w, p[9]);
        p[2] = fmaf(v, q1.x, p[2]);  p[10] = fmaf(-v, q1.y, p[10]);
        p[3] = fmaf(v, q1.z, p[3]);  p[11] = fmaf(-v, q1.w, p[11]);
        p[4] = fmaf(v, q2.x, p[4]);  p[12] = fmaf(-v, q2.y, p[12]);
        p[5] = fmaf(v, q2.z, p[5]);  p[13] = fmaf(-v, q2.w, p[13]);
        p[6] = fmaf(v, q3.x, p[6]);  p[14] = fmaf(-v, q3.y, p[14]);
        p[7] = fmaf(v, q3.z, p[7]);  p[15] = fmaf(-v, q3.w, p[15]);
    }
    block_reduce16(p, red, tid);
    if (tid < 128) {
        const int c = tid >> 3, ky = tid & 7;
        const float a = fc0_w[c];
        float gr = a * red[ky];
        float gi = a * red[8 + ky];
        if (ky == 0) gr += 512.f * fc0_b[c];
        const size_t idx = ((((size_t)b * NC + c) * NH + row) * NM + ky) * 2;
        G[idx] = gr;
        G[idx + 1] = gi;
    }
}

// ---------------------------------------------------------------------------
// k_B: X_ft[b,i,kx,ky] = (1/(H*W)) * sum_x G[b,i,x,ky] * e^{-2pi i kx x/512}
// ---------------------------------------------------------------------------
__global__ __launch_bounds__(256) void k_B(const float* __restrict__ G,
        const float* __restrict__ twd, float* __restrict__ Xft) {
    __shared__ float red[64];
    const int tid = threadIdx.x;
    const int kx = blockIdx.x & 7;
    const int ci = (blockIdx.x >> 3) & 15;
    const int b = blockIdx.x >> 7;
    const float* Gb = G + ((size_t)b * NC + ci) * NH * (NM * 2);

    float p[16];
    #pragma unroll
    for (int k = 0; k < 16; ++k) p[k] = 0.f;

    #pragma unroll
    for (int px = 0; px < 2; ++px) {
        const int xx = tid + px * 256;
        const float4* g4 = (const float4*)(Gb + (size_t)xx * 16);
        const float2 t = *(const float2*)(twd + (size_t)(((kx * xx) & 511) * 8 + 1) * 2);
        const float tr = t.x, ti = -t.y;   // e^{-2pi i kx x/512}
        #pragma unroll
        for (int q = 0; q < 4; ++q) {
            const float4 g = g4[q];
            const int ky = q * 2;
            p[ky]         += g.x * tr - g.y * ti;
            p[8 + ky]     += g.x * ti + g.y * tr;
            p[ky + 1]     += g.z * tr - g.w * ti;
            p[8 + ky + 1] += g.z * ti + g.w * tr;
        }
    }
    block_reduce16(p, red, tid);
    if (tid < 8) {
        const size_t o = ((((size_t)b * NC + ci) * NM + kx) * NM + tid) * 2;
        const float inv = 1.f / (512.f * 512.f);
        Xft[o] = red[tid] * inv;
        Xft[o + 1] = red[8 + tid] * inv;
    }
}

// ---------------------------------------------------------------------------
// k_F: F[b,o,kx,ky] = sum_i X[b,i,kx,ky] * (wr + i wi)[i,o,kx,ky]
// ---------------------------------------------------------------------------
__global__ __launch_bounds__(256) void k_F(const float* __restrict__ Xft,
        const float* __restrict__ wr, const float* __restrict__ wi,
        float* __restrict__ F) {
    const int b = blockIdx.x;
    const int tid = threadIdx.x;
    for (int k = 0; k < 4; ++k) {
        const int idx = tid + k * 256;
        const int o = idx >> 6, kk = idx & 63;  // kk = kx*8 + ky
        float fr = 0.f, fi = 0.f;
        #pragma unroll
        for (int i = 0; i < 16; ++i) {
            const size_t xi = (((size_t)b * NC + i) * 64 + kk) * 2;
            const float xr = Xft[xi], xim = Xft[xi + 1];
            const size_t widx = ((size_t)i * NC + o) * 64 + kk;
            const float wre = wr[widx], wim = wi[widx];
            fr += xr * wre - xim * wim;
            fi += xr * wim + xim * wre;
        }
        const size_t fo = (((size_t)b * NC + o) * 64 + kk) * 2;
        F[fo] = fr;
        F[fo + 1] = fi;
    }
}

// ---------------------------------------------------------------------------
// k_GV: per (b,row), thread=(o,ky).  Ṽ[o,ky] = sum_kx F e^{+i kx th_row}
// (Re only at ky=0).  Then:
//   MODE 0: G = 512Ṽ + C0*G + 512*cb0*δ ;  W  = P0*Ṽ
//   MODE 1: G = 512Ṽ + C1*G + 512*cb1*δ ;  W += C2*Ṽ   (Pd = C2)
//   MODE 2: W = c_ky * (W + Ṽ)           ;  no G update
// In-place G is safe: one block owns its (b,row); reads staged to LDS first.
// ---------------------------------------------------------------------------
template<int MODE>
__global__ __launch_bounds__(128) void k_GV(
        const float* __restrict__ F, const float* __restrict__ Pd,
        const float* __restrict__ Cd, const float* __restrict__ cbd,
        const float* __restrict__ twd,
        float* __restrict__ G, float* __restrict__ W) {
    __shared__ float G_s[16][16];   // [c][ky*2+ri]
    __shared__ float V_s[16][16];
    const int tid = threadIdx.x;    // 128
    const int b = blockIdx.x >> 9, row = blockIdx.x & 511;
    const int o = tid >> 3, ky = tid & 7;
    const size_t wIdx = (((size_t)(b * 16 + o) * 512 + row) * 8 + ky) * 2;

    if (MODE < 2) {
        const float2 g = *(const float2*)(G + wIdx);
        G_s[o][ky * 2] = g.x;
        G_s[o][ky * 2 + 1] = g.y;
    }
    const float* Fb = F + (size_t)b * 2048;
    float vr = 0.f, vi = 0.f;
    #pragma unroll
    for (int kx = 0; kx < 8; ++kx) {
        const float tc = twd[(row * 8 + kx) * 2];       // uniform -> s_load
        const float ts = twd[(row * 8 + kx) * 2 + 1];
        const float fr = Fb[(o * 64 + kx * 8 + ky) * 2];
        const float fi = Fb[(o * 64 + kx * 8 + ky) * 2 + 1];
        vr += fr * tc - fi * ts;
        vi += fr * ts + fi * tc;
    }
    if (ky == 0) vi = 0.f;          // c2r drops imag of bin 0
    V_s[o][ky * 2] = vr;
    V_s[o][ky * 2 + 1] = vi;
    __syncthreads();

    if (MODE < 2) {
        float gr = 512.f * vr, gi = 512.f * vi;
        float wr = 0.f, wi = 0.f;
        #pragma unroll
        for (int c = 0; c < 16; ++c) {
            const float cc = Cd[o * 16 + c];
            gr = fmaf(cc, G_s[c][ky * 2], gr);
            gi = fmaf(cc, G_s[c][ky * 2 + 1], gi);
            const float pc = Pd[o * 16 + c];
            wr = fmaf(pc, V_s[c][ky * 2], wr);
            wi = fmaf(pc, V_s[c][ky * 2 + 1], wi);
        }
        if (ky == 0) gr += 512.f * cbd[o];
        *(float2*)(G + wIdx) = make_float2(gr, gi);
        if (MODE == 0) {
            W[wIdx] = wr;
            W[wIdx + 1] = wi;
        } else {
            W[wIdx] += wr;
            W[wIdx + 1] += wi;
        }
    } else {
        const float ck = (ky == 0) ? 1.f : 2.f;   // fold Hermitian doubling
        W[wIdx]     = ck * (W[wIdx] + vr);
        W[wIdx + 1] = ck * (W[wIdx + 1] + vi);
    }
}

// ---------------------------------------------------------------------------
// k_head: the ONLY per-pixel kernel.
// h3[o,px] = Re sum_ky W[o,row,ky] e^{i ky th_w} + dvec[o]*x + evec[o]
// then fc1 -> relu -> fc2 -> out.  2 rows per block, 4 px/thread.
// ---------------------------------------------------------------------------
__global__ __launch_bounds__(256) void k_head(
        const float* __restrict__ x, const float* __restrict__ Wg,
        const float* __restrict__ dvec, const float* __restrict__ evec,
        const float* __restrict__ fc1_w, const float* __restrict__ fc1_b,
        const float* __restrict__ fc2_w, const float* __restrict__ fc2_b,
        const float* __restrict__ twd,
        float* __restrict__ out) {
    __shared__ float Wl[16][2][16];   // [o][row_local][ky*2+ri]

    const int tid = threadIdx.x;
    const int b = blockIdx.x >> 8;
    const int r0 = (blockIdx.x & 255) * 2;

    #pragma unroll
    for (int i = 0; i < 2; ++i) {
        const int idx = tid + i * 256;                 // 512 floats
        const int o = idx >> 5, rl = (idx >> 4) & 1, q = idx & 15;
        Wl[o][rl][q] = Wg[((size_t)(b * 16 + o) * 512 + r0 + rl) * 16 + q];
    }

    // per-pixel twiddles e^{+i ky th_w}, w = tid
    float cta[8], sta[8];
    {
        const float4* q = (const float4*)(twd + (size_t)tid * 16);
        const float4 q0 = q[0], q1 = q[1], q2 = q[2], q3 = q[3];
        cta[0] = q0.x; sta[0] = q0.y; cta[1] = q0.z; sta[1] = q0.w;
        cta[2] = q1.x; sta[2] = q1.y; cta[3] = q1.z; sta[3] = q1.w;
        cta[4] = q2.x; sta[4] = q2.y; cta[5] = q2.z; sta[5] = q2.w;
        cta[6] = q3.x; sta[6] = q3.y; cta[7] = q3.z; sta[7] = q3.w;
    }

    const float* xr0 = x + ((size_t)b * NH + r0) * NW;
    const float x0a = xr0[tid], x0b = xr0[tid + 256];
    const float x1a = xr0[NW + tid], x1b = xr0[NW + tid + 256];
    __syncthreads();

    // h3 for 4 pixels: rows r0,r1 at w=tid and w=tid+256 (parity trick)
    float h0a[16], h0b[16], h1a[16], h1b[16];
    #pragma unroll
    for (int o = 0; o < 16; ++o) {
        float er0 = 0.f, od0 = 0.f, er1 = 0.f, od1 = 0.f;
        #pragma unroll
        for (int ky = 0; ky < 8; ky += 2) {
            er0 = fmaf(Wl[o][0][ky * 2], cta[ky], er0);
            er0 = fmaf(-Wl[o][0][ky * 2 + 1], sta[ky], er0);
            od0 = fmaf(Wl[o][0][ky * 2 + 2], cta[ky + 1], od0);
            od0 = fmaf(-Wl[o][0][ky * 2 + 3], sta[ky + 1], od0);
            er1 = fmaf(Wl[o][1][ky * 2], cta[ky], er1);
            er1 = fmaf(-Wl[o][1][ky * 2 + 1], sta[ky], er1);
            od1 = fmaf(Wl[o][1][ky * 2 + 2], cta[ky + 1], od1);
            od1 = fmaf(-Wl[o][1][ky * 2 + 3], sta[ky + 1], od1);
        }
        const float dv = dvec[o], ev = evec[o];        // uniform -> s_load
        h0a[o] = (er0 + od0) + fmaf(dv, x0a, ev);
        h0b[o] = (er0 - od0) + fmaf(dv, x0b, ev);
        h1a[o] = (er1 + od1) + fmaf(dv, x1a, ev);
        h1b[o] = (er1 - od1) + fmaf(dv, x1b, ev);
    }

    float a0a = fc2_b[0], a0b = a0a, a1a = a0a, a1b = a0a;
    #pragma unroll 8
    for (int hd = 0; hd < NHID; ++hd) {
        const float bi = fc1_b[hd];                    // uniform -> s_load
        float s0a = bi, s0b = bi, s1a = bi, s1b = bi;
        #pragma unroll
        for (int c = 0; c < 16; ++c) {
            const float wv = fc1_w[c * 64 + hd];       // uniform -> s_load
            s0a = fmaf(wv, h0a[c], s0a);
            s0b = fmaf(wv, h0b[c], s0b);
            s1a = fmaf(wv, h1a[c], s1a);
            s1b = fmaf(wv, h1b[c], s1b);
        }
        const float w2 = fc2_w[hd];
        a0a = fmaf(fmaxf(s0a, 0.f), w2, a0a);
        a0b = fmaf(fmaxf(s0b, 0.f), w2, a0b);
        a1a = fmaf(fmaxf(s1a, 0.f), w2, a1a);
        a1b = fmaf(fmaxf(s1b, 0.f), w2, a1b);
    }
    float* op = out + ((size_t)b * NH + r0) * NW;
    op[tid] = a0a;
    op[tid + 256] = a0b;
    op[NW + tid] = a1a;
    op[NW + tid + 256] = a1b;
}

// ---------------------------------------------------------------------------
extern "C" void kernel_launch(void* const* d_in, const int* in_sizes, int n_in,
                              void* d_out, int out_size, void* d_ws, size_t ws_size,
                              hipStream_t stream) {
    const float* x       = (const float*)d_in[0];
    const float* fc0_w   = (const float*)d_in[1];
    const float* fc0_b   = (const float*)d_in[2];
    const float* spec_wr = (const float*)d_in[3];
    const float* spec_wi = (const float*)d_in[4];
    const float* conv_w  = (const float*)d_in[5];
    const float* conv_b  = (const float*)d_in[6];
    const float* fc1_w   = (const float*)d_in[7];
    const float* fc1_b   = (const float*)d_in[8];
    const float* fc2_w   = (const float*)d_in[9];
    const float* fc2_b   = (const float*)d_in[10];
    float* out = (float*)d_out;

    char* ws = (char*)d_ws;
    size_t off = 0;
    float* G    = (float*)(ws + off); off += (size_t)NB * NC * NH * NM * 2 * 4;  // 4 MB
    float* Wbuf = (float*)(ws + off); off += (size_t)NB * NC * NH * NM * 2 * 4;  // 4 MB
    float* Xft  = (float*)(ws + off); off += (size_t)NB * NC * NM * NM * 2 * 4;
    float* F    = (float*)(ws + off); off += (size_t)NB * NC * NM * NM * 2 * 4;
    float* twd  = (float*)(ws + off); off += (size_t)NH * NM * 2 * 4;            // 32 KB
    float* P0   = (float*)(ws + off); off += 256 * 4;
    float* dvec = (float*)(ws + off); off += 16 * 4;
    float* evec = (float*)(ws + off); off += 16 * 4;

    k_tw<<<16, 256, 0, stream>>>(twd);
    k_prep<<<1, 256, 0, stream>>>(conv_w, conv_b, fc0_w, fc0_b, P0, dvec, evec);
    k_g0<<<NB * NH, 256, 0, stream>>>(x, fc0_w, fc0_b, twd, G);

    const float* C2 = conv_w + 512;
    for (int d = 0; d < NDEPTH; ++d) {
        k_B<<<NB * NC * NM, 256, 0, stream>>>(G, twd, Xft);
        k_F<<<NB, 256, 0, stream>>>(Xft, spec_wr + (size_t)d * NC * NC * NM * NM,
                                    spec_wi + (size_t)d * NC * NC * NM * NM, F);
        if (d == 0) {
            k_GV<0><<<NB * NH, 128, 0, stream>>>(F, P0, conv_w, conv_b, twd, G, Wbuf);
        } else if (d == 1) {
            k_GV<1><<<NB * NH, 128, 0, stream>>>(F, C2, conv_w + 256, conv_b + 16, twd, G, Wbuf);
        } else {
            k_GV<2><<<NB * NH, 128, 0, stream>>>(F, nullptr, nullptr, nullptr, twd, G, Wbuf);
        }
    }
    k_head<<<NB * NH / 2, 256, 0, stream>>>(x, Wbuf, dvec, evec,
                                            fc1_w, fc1_b, fc2_w, fc2_b, twd, out);
}

// Round 4
// 222.095 us; speedup vs baseline: 1.8956x; 1.1811x over previous
//
#include <hip/hip_runtime.h>
#include <math.h>

#define NB 8
#define NC 16
#define NH 512
#define NW 512
#define NM 8
#define NHID 64
#define NDEPTH 3

// 2*pi/512
#define ANG512 0.01227184630308513f

// ---------------------------------------------------------------------------
// k_twprep: blocks 0..15 build the exact twiddle table
//   twd[(w*8+k)*2 + {0,1}] = cos/sin(ANG*w*k)  (angle reduced mod 512)
// block 16 builds composite conv-chain matrices:
//   P0 = C2*C1;  dvec = P0*C0*fc0_w;  evec = P0*(C0*fc0_b + cb0) + C2*cb1 + cb2
// ---------------------------------------------------------------------------
__global__ __launch_bounds__(256) void k_twprep(
        const float* __restrict__ conv_w, const float* __restrict__ conv_b,
        const float* __restrict__ fc0_w, const float* __restrict__ fc0_b,
        float* __restrict__ twd, float* __restrict__ P0,
        float* __restrict__ dvec, float* __restrict__ evec) {
    if (blockIdx.x < 16) {
        const int idx = blockIdx.x * 256 + threadIdx.x;   // 0..4095 = w*8+k
        const int w = idx >> 3, k = idx & 7;
        const float ang = ANG512 * (float)((w * k) & 511);
        twd[idx * 2]     = cosf(ang);
        twd[idx * 2 + 1] = sinf(ang);
        return;
    }
    __shared__ float P_s[256];
    __shared__ float u_s[16];   // C0*fc0_w
    __shared__ float v_s[16];   // C0*fc0_b
    const int t = threadIdx.x;
    const float* C0 = conv_w;
    const float* C1 = conv_w + 256;
    const float* C2 = conv_w + 512;
    {
        const int o = t >> 4, c = t & 15;
        float s = 0.f;
        for (int k = 0; k < 16; ++k) s += C2[o * 16 + k] * C1[k * 16 + c];
        P_s[t] = s;
        P0[t] = s;
    }
    if (t < 16) {
        float s = 0.f, sb = 0.f;
        for (int c = 0; c < 16; ++c) {
            s  += C0[t * 16 + c] * fc0_w[c];
            sb += C0[t * 16 + c] * fc0_b[c];
        }
        u_s[t] = s;
        v_s[t] = sb;
    }
    __syncthreads();
    if (t < 16) {
        float dv = 0.f, ev = conv_b[32 + t];   // cb2[t]
        for (int k = 0; k < 16; ++k) {
            dv += P_s[t * 16 + k] * u_s[k];
            ev += P_s[t * 16 + k] * (v_s[k] + conv_b[k]);      // + P0*(C0*fc0_b + cb0)
            ev += C2[t * 16 + k] * conv_b[16 + k];             // + C2*cb1
        }
        dvec[t] = dv;
        evec[t] = ev;
    }
}

// ---------------------------------------------------------------------------
// block-wide reduction of 16 floats across 256 threads (4 waves).
// ---------------------------------------------------------------------------
__device__ __forceinline__ void block_reduce16(float* v, float* lds, int tid) {
    #pragma unroll
    for (int off = 32; off > 0; off >>= 1) {
        #pragma unroll
        for (int k = 0; k < 16; ++k) v[k] += __shfl_down(v[k], off);
    }
    const int wave = tid >> 6;
    if ((tid & 63) == 0) {
        #pragma unroll
        for (int k = 0; k < 16; ++k) lds[wave * 16 + k] = v[k];
    }
    __syncthreads();
    if (tid < 16) {
        lds[tid] = lds[tid] + lds[16 + tid] + lds[32 + tid] + lds[48 + tid];
    }
    __syncthreads();
}

// ---------------------------------------------------------------------------
// k_g0: row-DFT of x folded through the affine lift.
// G0[b,c,row,ky] = fc0_w[c]*Xrow[ky] + 512*fc0_b[c]*(ky==0)
// ---------------------------------------------------------------------------
__global__ __launch_bounds__(256) void k_g0(const float* __restrict__ x,
        const float* __restrict__ fc0_w, const float* __restrict__ fc0_b,
        const float* __restrict__ twd, float* __restrict__ G) {
    __shared__ float red[64];
    const int tid = threadIdx.x;
    const int b = blockIdx.x >> 9;
    const int row = blockIdx.x & 511;
    const float* xr = x + ((size_t)b * NH + row) * NW;

    float p[16];
    #pragma unroll
    for (int k = 0; k < 16; ++k) p[k] = 0.f;

    #pragma unroll
    for (int px = 0; px < 2; ++px) {
        const int w = tid + px * 256;
        const float v = xr[w];
        const float4* q = (const float4*)(twd + (size_t)w * 16);
        const float4 q0 = q[0], q1 = q[1], q2 = q[2], q3 = q[3];
        p[0] += v;
        p[1] = fmaf(v, q0.z, p[1]);  p[9]  = fmaf(-v, q0.w, p[9]);
        p[2] = fmaf(v, q1.x, p[2]);  p[10] = fmaf(-v, q1.y, p[10]);
        p[3] = fmaf(v, q1.z, p[3]);  p[11] = fmaf(-v, q1.w, p[11]);
        p[4] = fmaf(v, q2.x, p[4]);  p[12] = fmaf(-v, q2.y, p[12]);
        p[5] = fmaf(v, q2.z, p[5]);  p[13] = fmaf(-v, q2.w, p[13]);
        p[6] = fmaf(v, q3.x, p[6]);  p[14] = fmaf(-v, q3.y, p[14]);
        p[7] = fmaf(v, q3.z, p[7]);  p[15] = fmaf(-v, q3.w, p[15]);
    }
    block_reduce16(p, red, tid);
    if (tid < 128) {
        const int c = tid >> 3, ky = tid & 7;
        const float a = fc0_w[c];
        float gr = a * red[ky];
        float gi = a * red[8 + ky];
        if (ky == 0) gr += 512.f * fc0_b[c];
        const size_t idx = ((((size_t)b * NC + c) * NH + row) * NM + ky) * 2;
        G[idx] = gr;
        G[idx + 1] = gi;
    }
}

// ---------------------------------------------------------------------------
// k_B: X0[b,i,kx,ky] = (1/(H*W)) * sum_x G[b,i,x,ky] * e^{-2pi i kx x/512}
// ---------------------------------------------------------------------------
__global__ __launch_bounds__(256) void k_B(const float* __restrict__ G,
        const float* __restrict__ twd, float* __restrict__ Xft) {
    __shared__ float red[64];
    const int tid = threadIdx.x;
    const int kx = blockIdx.x & 7;
    const int ci = (blockIdx.x >> 3) & 15;
    const int b = blockIdx.x >> 7;
    const float* Gb = G + ((size_t)b * NC + ci) * NH * (NM * 2);

    float p[16];
    #pragma unroll
    for (int k = 0; k < 16; ++k) p[k] = 0.f;

    #pragma unroll
    for (int px = 0; px < 2; ++px) {
        const int xx = tid + px * 256;
        const float4* g4 = (const float4*)(Gb + (size_t)xx * 16);
        const float2 t = *(const float2*)(twd + (size_t)(((kx * xx) & 511) * 8 + 1) * 2);
        const float tr = t.x, ti = -t.y;   // e^{-2pi i kx x/512}
        #pragma unroll
        for (int q = 0; q < 4; ++q) {
            const float4 g = g4[q];
            const int ky = q * 2;
            p[ky]         += g.x * tr - g.y * ti;
            p[8 + ky]     += g.x * ti + g.y * tr;
            p[ky + 1]     += g.z * tr - g.w * ti;
            p[8 + ky + 1] += g.z * ti + g.w * tr;
        }
    }
    block_reduce16(p, red, tid);
    if (tid < 8) {
        const size_t o = ((((size_t)b * NC + ci) * NM + kx) * NM + tid) * 2;
        const float inv = 1.f / (512.f * 512.f);
        Xft[o] = red[tid] * inv;
        Xft[o + 1] = red[8 + tid] * inv;
    }
}

// ---------------------------------------------------------------------------
// k_modes: the entire 3-layer loop in mode space. One block per batch.
// Recurrence (kk = kx*8+ky):
//   F_d = X_d · w_d                                (complex, per (o,kk))
//   X_{d+1} = F̃_d + C_d X_d + cb_d δ_{kk0}
//     F̃ = F except ky=0 col: kx=0 -> (Re F, 0); kx>0 -> F/2   (Re-in-row-space)
//   Acoef = c_ky (F_2 + C2 F_1 + (C2C1) F_0)
// ---------------------------------------------------------------------------
__global__ __launch_bounds__(256) void k_modes(
        const float* __restrict__ Xft,
        const float* __restrict__ spec_wr, const float* __restrict__ spec_wi,
        const float* __restrict__ conv_w, const float* __restrict__ conv_b,
        const float* __restrict__ P0g,
        float* __restrict__ Acoef) {
    __shared__ float Xr[16][64], Xi[16][64];
    __shared__ float Fr[16][64], Fi[16][64];
    __shared__ float Ar[16][64], Ai[16][64];
    __shared__ float Pm[2][256];   // d=0: P0=C2C1, d=1: C2 (d=2 is identity)

    const int b = blockIdx.x;
    const int tid = threadIdx.x;

    #pragma unroll
    for (int k = 0; k < 4; ++k) {
        const int idx = tid + k * 256;
        const int i = idx >> 6, kk = idx & 63;
        const float2 v = *(const float2*)(Xft + ((size_t)(b * 16 + i) * 64 + kk) * 2);
        Xr[i][kk] = v.x; Xi[i][kk] = v.y;
        Ar[i][kk] = 0.f; Ai[i][kk] = 0.f;
    }
    Pm[0][tid] = P0g[tid];
    Pm[1][tid] = conv_w[512 + tid];   // C2
    __syncthreads();

    for (int d = 0; d < NDEPTH; ++d) {
        const float* wrp = spec_wr + (size_t)d * 4096;
        const float* wip = spec_wi + (size_t)d * 4096;
        // ---- F = X · w_d ----
        float fr4[4], fi4[4];
        #pragma unroll
        for (int k = 0; k < 4; ++k) {
            const int idx = tid + k * 256;
            const int o = idx >> 6, kk = idx & 63;
            float fr = 0.f, fi = 0.f;
            #pragma unroll
            for (int i = 0; i < 16; ++i) {
                const float xr = Xr[i][kk], xi = Xi[i][kk];
                const float wre = wrp[(i * 16 + o) * 64 + kk];
                const float wim = wip[(i * 16 + o) * 64 + kk];
                fr += xr * wre - xi * wim;
                fi += xr * wim + xi * wre;
            }
            fr4[k] = fr; fi4[k] = fi;
        }
        __syncthreads();   // everyone done reading X (for F) before F-write races nothing, but
                           // needed so prior-layer readers of F are done
        #pragma unroll
        for (int k = 0; k < 4; ++k) {
            const int idx = tid + k * 256;
            const int o = idx >> 6, kk = idx & 63;
            Fr[o][kk] = fr4[k]; Fi[o][kk] = fi4[k];
        }
        __syncthreads();

        // ---- A += P_d F ;  Xnew = F̃ + C_d X + cb_d δ ----
        float xnr[4], xni[4];
        #pragma unroll
        for (int k = 0; k < 4; ++k) {
            const int idx = tid + k * 256;
            const int o = idx >> 6, kk = idx & 63;
            float ar, ai;
            if (d == 2) {
                ar = Fr[o][kk]; ai = Fi[o][kk];
            } else {
                ar = 0.f; ai = 0.f;
                #pragma unroll
                for (int c = 0; c < 16; ++c) {
                    const float p = Pm[d][o * 16 + c];
                    ar = fmaf(p, Fr[c][kk], ar);
                    ai = fmaf(p, Fi[c][kk], ai);
                }
            }
            Ar[o][kk] += ar; Ai[o][kk] += ai;

            if (d < 2) {
                const float* Cd = conv_w + d * 256;
                const int ky = kk & 7, kx = kk >> 3;
                float xr, xi;
                if (ky == 0) {
                    if (kx == 0) { xr = Fr[o][kk]; xi = 0.f; }
                    else         { xr = 0.5f * Fr[o][kk]; xi = 0.5f * Fi[o][kk]; }
                } else { xr = Fr[o][kk]; xi = Fi[o][kk]; }
                #pragma unroll
                for (int c = 0; c < 16; ++c) {
                    const float cc = Cd[o * 16 + c];
                    xr = fmaf(cc, Xr[c][kk], xr);
                    xi = fmaf(cc, Xi[c][kk], xi);
                }
                if (kk == 0) xr += conv_b[d * 16 + o];
                xnr[k] = xr; xni[k] = xi;
            }
        }
        __syncthreads();
        if (d < 2) {
            #pragma unroll
            for (int k = 0; k < 4; ++k) {
                const int idx = tid + k * 256;
                const int o = idx >> 6, kk = idx & 63;
                Xr[o][kk] = xnr[k]; Xi[o][kk] = xni[k];
            }
            __syncthreads();
        }
    }

    #pragma unroll
    for (int k = 0; k < 4; ++k) {
        const int idx = tid + k * 256;
        const int o = idx >> 6, kk = idx & 63;
        const float ck = ((kk & 7) == 0) ? 1.f : 2.f;   // Hermitian doubling (W axis)
        *(float2*)(Acoef + ((size_t)(b * 16 + o) * 64 + kk) * 2) =
            make_float2(ck * Ar[o][kk], ck * Ai[o][kk]);
    }
}

// ---------------------------------------------------------------------------
// k_head: the ONLY per-pixel kernel. One (b,row) per block, 2 px/thread.
// W(row)[o,ky] = sum_kx Acoef[b,o,kx,ky] e^{+i kx th_row}   (in-kernel)
// h3[o,px] = Re sum_ky W e^{i ky th_w} + dvec[o]*x + evec[o]
// then fc1 -> relu -> fc2 -> out.
// __launch_bounds__(256,4): keep 32 live h-floats in VGPRs (no spill).
// ---------------------------------------------------------------------------
__global__ __launch_bounds__(256, 4) void k_head(
        const float* __restrict__ x, const float* __restrict__ Acoef,
        const float* __restrict__ dvec, const float* __restrict__ evec,
        const float* __restrict__ fc1_w, const float* __restrict__ fc1_b,
        const float* __restrict__ fc2_w, const float* __restrict__ fc2_b,
        const float* __restrict__ twd,
        float* __restrict__ out) {
    __shared__ float Wrow[16][16];   // [o][ky*2+ri]

    const int tid = threadIdx.x;
    const int b = blockIdx.x >> 9;
    const int row = blockIdx.x & 511;

    if (tid < 128) {
        const int o = tid >> 3, ky = tid & 7;
        const float* Ab = Acoef + ((size_t)(b * 16 + o) * 64 + ky) * 2;
        float wr = 0.f, wi = 0.f;
        #pragma unroll
        for (int kx = 0; kx < 8; ++kx) {
            const float tc = twd[(row * 8 + kx) * 2];       // uniform -> s_load
            const float ts = twd[(row * 8 + kx) * 2 + 1];
            const float ar = Ab[kx * 16], ai = Ab[kx * 16 + 1];
            wr += ar * tc - ai * ts;
            wi += ar * ts + ai * tc;
        }
        Wrow[o][ky * 2] = wr;
        Wrow[o][ky * 2 + 1] = wi;   // ky=0 imag unused downstream (sta[0]=0)
    }

    const float* xrp = x + ((size_t)b * NH + row) * NW;
    const float xa = xrp[tid], xb = xrp[tid + 256];

    float cta[8], sta[8];
    {
        const float4* q = (const float4*)(twd + (size_t)tid * 16);
        const float4 q0 = q[0], q1 = q[1], q2 = q[2], q3 = q[3];
        cta[0] = q0.x; sta[0] = q0.y; cta[1] = q0.z; sta[1] = q0.w;
        cta[2] = q1.x; sta[2] = q1.y; cta[3] = q1.z; sta[3] = q1.w;
        cta[4] = q2.x; sta[4] = q2.y; cta[5] = q2.z; sta[5] = q2.w;
        cta[6] = q3.x; sta[6] = q3.y; cta[7] = q3.z; sta[7] = q3.w;
    }
    __syncthreads();

    // h3 for 2 pixels: w=tid and w=tid+256 (parity trick: tw(w+256)=(-1)^ky tw(w))
    float ha[16], hb[16];
    #pragma unroll
    for (int o = 0; o < 16; ++o) {
        float er = 0.f, od = 0.f;
        #pragma unroll
        for (int ky = 0; ky < 8; ky += 2) {
            er = fmaf(Wrow[o][ky * 2], cta[ky], er);
            er = fmaf(-Wrow[o][ky * 2 + 1], sta[ky], er);
            od = fmaf(Wrow[o][ky * 2 + 2], cta[ky + 1], od);
            od = fmaf(-Wrow[o][ky * 2 + 3], sta[ky + 1], od);
        }
        const float dv = dvec[o], ev = evec[o];        // uniform -> s_load
        ha[o] = (er + od) + fmaf(dv, xa, ev);
        hb[o] = (er - od) + fmaf(dv, xb, ev);
    }

    float aa = fc2_b[0], ab = aa;
    #pragma unroll 8
    for (int hd = 0; hd < NHID; ++hd) {
        const float bi = fc1_b[hd];                    // uniform -> s_load
        float sa = bi, sb = bi;
        #pragma unroll
        for (int c = 0; c < 16; ++c) {
            const float wv = fc1_w[c * 64 + hd];       // uniform -> s_load
            sa = fmaf(wv, ha[c], sa);
            sb = fmaf(wv, hb[c], sb);
        }
        const float w2 = fc2_w[hd];
        aa = fmaf(fmaxf(sa, 0.f), w2, aa);
        ab = fmaf(fmaxf(sb, 0.f), w2, ab);
    }
    float* op = out + ((size_t)b * NH + row) * NW;
    op[tid] = aa;
    op[tid + 256] = ab;
}

// ---------------------------------------------------------------------------
extern "C" void kernel_launch(void* const* d_in, const int* in_sizes, int n_in,
                              void* d_out, int out_size, void* d_ws, size_t ws_size,
                              hipStream_t stream) {
    const float* x       = (const float*)d_in[0];
    const float* fc0_w   = (const float*)d_in[1];
    const float* fc0_b   = (const float*)d_in[2];
    const float* spec_wr = (const float*)d_in[3];
    const float* spec_wi = (const float*)d_in[4];
    const float* conv_w  = (const float*)d_in[5];
    const float* conv_b  = (const float*)d_in[6];
    const float* fc1_w   = (const float*)d_in[7];
    const float* fc1_b   = (const float*)d_in[8];
    const float* fc2_w   = (const float*)d_in[9];
    const float* fc2_b   = (const float*)d_in[10];
    float* out = (float*)d_out;

    char* ws = (char*)d_ws;
    size_t off = 0;
    float* G     = (float*)(ws + off); off += (size_t)NB * NC * NH * NM * 2 * 4;  // 4 MB
    float* Xft   = (float*)(ws + off); off += (size_t)NB * NC * NM * NM * 2 * 4;  // 64 KB
    float* Acoef = (float*)(ws + off); off += (size_t)NB * NC * NM * NM * 2 * 4;  // 64 KB
    float* twd   = (float*)(ws + off); off += (size_t)NH * NM * 2 * 4;            // 32 KB
    float* P0    = (float*)(ws + off); off += 256 * 4;
    float* dvec  = (float*)(ws + off); off += 16 * 4;
    float* evec  = (float*)(ws + off); off += 16 * 4;

    k_twprep<<<17, 256, 0, stream>>>(conv_w, conv_b, fc0_w, fc0_b, twd, P0, dvec, evec);
    k_g0<<<NB * NH, 256, 0, stream>>>(x, fc0_w, fc0_b, twd, G);
    k_B<<<NB * NC * NM, 256, 0, stream>>>(G, twd, Xft);
    k_modes<<<NB, 256, 0, stream>>>(Xft, spec_wr, spec_wi, conv_w, conv_b, P0, Acoef);
    k_head<<<NB * NH, 256, 0, stream>>>(x, Acoef, dvec, evec,
                                        fc1_w, fc1_b, fc2_w, fc2_b, twd, out);
}

// Round 5
// 205.004 us; speedup vs baseline: 2.0537x; 1.0834x over previous
//
#include <hip/hip_runtime.h>
#include <math.h>

#define NB 8
#define NC 16
#define NH 512
#define NW 512
#define NM 8
#define NHID 64
#define NDEPTH 3

// 2*pi/512
#define ANG512 0.01227184630308513f

// ---------------------------------------------------------------------------
// k_twprep: blocks 0..15 build the exact twiddle table
//   twd[(w*8+k)*2 + {0,1}] = cos/sin(ANG*w*k)  (angle reduced mod 512)
// block 16 builds composite conv-chain matrices:
//   P0 = C2*C1;  dvec = P0*C0*fc0_w;  evec = P0*(C0*fc0_b + cb0) + C2*cb1 + cb2
// ---------------------------------------------------------------------------
__global__ __launch_bounds__(256) void k_twprep(
        const float* __restrict__ conv_w, const float* __restrict__ conv_b,
        const float* __restrict__ fc0_w, const float* __restrict__ fc0_b,
        float* __restrict__ twd, float* __restrict__ P0,
        float* __restrict__ dvec, float* __restrict__ evec) {
    if (blockIdx.x < 16) {
        const int idx = blockIdx.x * 256 + threadIdx.x;   // 0..4095 = w*8+k
        const int w = idx >> 3, k = idx & 7;
        const float ang = ANG512 * (float)((w * k) & 511);
        twd[idx * 2]     = cosf(ang);
        twd[idx * 2 + 1] = sinf(ang);
        return;
    }
    __shared__ float P_s[256];
    __shared__ float u_s[16];   // C0*fc0_w
    __shared__ float v_s[16];   // C0*fc0_b
    const int t = threadIdx.x;
    const float* C0 = conv_w;
    const float* C1 = conv_w + 256;
    const float* C2 = conv_w + 512;
    {
        const int o = t >> 4, c = t & 15;
        float s = 0.f;
        for (int k = 0; k < 16; ++k) s += C2[o * 16 + k] * C1[k * 16 + c];
        P_s[t] = s;
        P0[t] = s;
    }
    if (t < 16) {
        float s = 0.f, sb = 0.f;
        for (int c = 0; c < 16; ++c) {
            s  += C0[t * 16 + c] * fc0_w[c];
            sb += C0[t * 16 + c] * fc0_b[c];
        }
        u_s[t] = s;
        v_s[t] = sb;
    }
    __syncthreads();
    if (t < 16) {
        float dv = 0.f, ev = conv_b[32 + t];   // cb2[t]
        for (int k = 0; k < 16; ++k) {
            dv += P_s[t * 16 + k] * u_s[k];
            ev += P_s[t * 16 + k] * (v_s[k] + conv_b[k]);      // + P0*(C0*fc0_b + cb0)
            ev += C2[t * 16 + k] * conv_b[16 + k];             // + C2*cb1
        }
        dvec[t] = dv;
        evec[t] = ev;
    }
}

// ---------------------------------------------------------------------------
// block-wide reduction of 16 floats across 256 threads (4 waves).
// ---------------------------------------------------------------------------
__device__ __forceinline__ void block_reduce16(float* v, float* lds, int tid) {
    #pragma unroll
    for (int off = 32; off > 0; off >>= 1) {
        #pragma unroll
        for (int k = 0; k < 16; ++k) v[k] += __shfl_down(v[k], off);
    }
    const int wave = tid >> 6;
    if ((tid & 63) == 0) {
        #pragma unroll
        for (int k = 0; k < 16; ++k) lds[wave * 16 + k] = v[k];
    }
    __syncthreads();
    if (tid < 16) {
        lds[tid] = lds[tid] + lds[16 + tid] + lds[32 + tid] + lds[48 + tid];
    }
    __syncthreads();
}

// ---------------------------------------------------------------------------
// k_g0: row-DFT of x folded through the affine lift.
// G0[b,c,row,ky] = fc0_w[c]*Xrow[ky] + 512*fc0_b[c]*(ky==0)
// ---------------------------------------------------------------------------
__global__ __launch_bounds__(256) void k_g0(const float* __restrict__ x,
        const float* __restrict__ fc0_w, const float* __restrict__ fc0_b,
        const float* __restrict__ twd, float* __restrict__ G) {
    __shared__ float red[64];
    const int tid = threadIdx.x;
    const int b = blockIdx.x >> 9;
    const int row = blockIdx.x & 511;
    const float* xr = x + ((size_t)b * NH + row) * NW;

    float p[16];
    #pragma unroll
    for (int k = 0; k < 16; ++k) p[k] = 0.f;

    #pragma unroll
    for (int px = 0; px < 2; ++px) {
        const int w = tid + px * 256;
        const float v = xr[w];
        const float4* q = (const float4*)(twd + (size_t)w * 16);
        const float4 q0 = q[0], q1 = q[1], q2 = q[2], q3 = q[3];
        p[0] += v;
        p[1] = fmaf(v, q0.z, p[1]);  p[9]  = fmaf(-v, q0.w, p[9]);
        p[2] = fmaf(v, q1.x, p[2]);  p[10] = fmaf(-v, q1.y, p[10]);
        p[3] = fmaf(v, q1.z, p[3]);  p[11] = fmaf(-v, q1.w, p[11]);
        p[4] = fmaf(v, q2.x, p[4]);  p[12] = fmaf(-v, q2.y, p[12]);
        p[5] = fmaf(v, q2.z, p[5]);  p[13] = fmaf(-v, q2.w, p[13]);
        p[6] = fmaf(v, q3.x, p[6]);  p[14] = fmaf(-v, q3.y, p[14]);
        p[7] = fmaf(v, q3.z, p[7]);  p[15] = fmaf(-v, q3.w, p[15]);
    }
    block_reduce16(p, red, tid);
    if (tid < 128) {
        const int c = tid >> 3, ky = tid & 7;
        const float a = fc0_w[c];
        float gr = a * red[ky];
        float gi = a * red[8 + ky];
        if (ky == 0) gr += 512.f * fc0_b[c];
        const size_t idx = ((((size_t)b * NC + c) * NH + row) * NM + ky) * 2;
        G[idx] = gr;
        G[idx + 1] = gi;
    }
}

// ---------------------------------------------------------------------------
// k_B: X0[b,i,kx,ky] = (1/(H*W)) * sum_x G[b,i,x,ky] * e^{-2pi i kx x/512}
// ---------------------------------------------------------------------------
__global__ __launch_bounds__(256) void k_B(const float* __restrict__ G,
        const float* __restrict__ twd, float* __restrict__ Xft) {
    __shared__ float red[64];
    const int tid = threadIdx.x;
    const int kx = blockIdx.x & 7;
    const int ci = (blockIdx.x >> 3) & 15;
    const int b = blockIdx.x >> 7;
    const float* Gb = G + ((size_t)b * NC + ci) * NH * (NM * 2);

    float p[16];
    #pragma unroll
    for (int k = 0; k < 16; ++k) p[k] = 0.f;

    #pragma unroll
    for (int px = 0; px < 2; ++px) {
        const int xx = tid + px * 256;
        const float4* g4 = (const float4*)(Gb + (size_t)xx * 16);
        const float2 t = *(const float2*)(twd + (size_t)(((kx * xx) & 511) * 8 + 1) * 2);
        const float tr = t.x, ti = -t.y;   // e^{-2pi i kx x/512}
        #pragma unroll
        for (int q = 0; q < 4; ++q) {
            const float4 g = g4[q];
            const int ky = q * 2;
            p[ky]         += g.x * tr - g.y * ti;
            p[8 + ky]     += g.x * ti + g.y * tr;
            p[ky + 1]     += g.z * tr - g.w * ti;
            p[8 + ky + 1] += g.z * ti + g.w * tr;
        }
    }
    block_reduce16(p, red, tid);
    if (tid < 8) {
        const size_t o = ((((size_t)b * NC + ci) * NM + kx) * NM + tid) * 2;
        const float inv = 1.f / (512.f * 512.f);
        Xft[o] = red[tid] * inv;
        Xft[o + 1] = red[8 + tid] * inv;
    }
}

// ---------------------------------------------------------------------------
// k_modes: the entire 3-layer loop in mode space. One block per batch.
//   F_d = X_d · w_d ;  X_{d+1} = F̃_d + C_d X_d + cb_d δ_{kk0}
//   A = F_2 + C2 F_1 + (C2C1) F_0
// Epilogue folds fc1 in: AH[hd,ky,kx] = c_ky * sum_c fc1[c,hd] A[c,kx*8+ky],
// block 0 also: gvec = fc1^T dvec, Kvec = fc1_b + fc1^T evec.
// ---------------------------------------------------------------------------
__global__ __launch_bounds__(256) void k_modes(
        const float* __restrict__ Xft,
        const float* __restrict__ spec_wr, const float* __restrict__ spec_wi,
        const float* __restrict__ conv_w, const float* __restrict__ conv_b,
        const float* __restrict__ P0g,
        const float* __restrict__ fc1_w, const float* __restrict__ fc1_b,
        const float* __restrict__ dvec, const float* __restrict__ evec,
        float* __restrict__ AH, float* __restrict__ gvec, float* __restrict__ Kvec) {
    __shared__ float Xr[16][64], Xi[16][64];
    __shared__ float Fr[16][64], Fi[16][64];
    __shared__ float Ar[16][64], Ai[16][64];
    __shared__ float Pm[2][256];   // d=0: P0=C2C1, d=1: C2 (d=2 is identity)

    const int b = blockIdx.x;
    const int tid = threadIdx.x;

    #pragma unroll
    for (int k = 0; k < 4; ++k) {
        const int idx = tid + k * 256;
        const int i = idx >> 6, kk = idx & 63;
        const float2 v = *(const float2*)(Xft + ((size_t)(b * 16 + i) * 64 + kk) * 2);
        Xr[i][kk] = v.x; Xi[i][kk] = v.y;
        Ar[i][kk] = 0.f; Ai[i][kk] = 0.f;
    }
    Pm[0][tid] = P0g[tid];
    Pm[1][tid] = conv_w[512 + tid];   // C2
    __syncthreads();

    for (int d = 0; d < NDEPTH; ++d) {
        const float* wrp = spec_wr + (size_t)d * 4096;
        const float* wip = spec_wi + (size_t)d * 4096;
        // ---- F = X · w_d ----
        float fr4[4], fi4[4];
        #pragma unroll
        for (int k = 0; k < 4; ++k) {
            const int idx = tid + k * 256;
            const int o = idx >> 6, kk = idx & 63;
            float fr = 0.f, fi = 0.f;
            #pragma unroll
            for (int i = 0; i < 16; ++i) {
                const float xr = Xr[i][kk], xi = Xi[i][kk];
                const float wre = wrp[(i * 16 + o) * 64 + kk];
                const float wim = wip[(i * 16 + o) * 64 + kk];
                fr += xr * wre - xi * wim;
                fi += xr * wim + xi * wre;
            }
            fr4[k] = fr; fi4[k] = fi;
        }
        __syncthreads();
        #pragma unroll
        for (int k = 0; k < 4; ++k) {
            const int idx = tid + k * 256;
            const int o = idx >> 6, kk = idx & 63;
            Fr[o][kk] = fr4[k]; Fi[o][kk] = fi4[k];
        }
        __syncthreads();

        // ---- A += P_d F ;  Xnew = F̃ + C_d X + cb_d δ ----
        float xnr[4], xni[4];
        #pragma unroll
        for (int k = 0; k < 4; ++k) {
            const int idx = tid + k * 256;
            const int o = idx >> 6, kk = idx & 63;
            float ar, ai;
            if (d == 2) {
                ar = Fr[o][kk]; ai = Fi[o][kk];
            } else {
                ar = 0.f; ai = 0.f;
                #pragma unroll
                for (int c = 0; c < 16; ++c) {
                    const float p = Pm[d][o * 16 + c];
                    ar = fmaf(p, Fr[c][kk], ar);
                    ai = fmaf(p, Fi[c][kk], ai);
                }
            }
            Ar[o][kk] += ar; Ai[o][kk] += ai;

            if (d < 2) {
                const float* Cd = conv_w + d * 256;
                const int ky = kk & 7, kx = kk >> 3;
                float xr, xi;
                if (ky == 0) {
                    if (kx == 0) { xr = Fr[o][kk]; xi = 0.f; }
                    else         { xr = 0.5f * Fr[o][kk]; xi = 0.5f * Fi[o][kk]; }
                } else { xr = Fr[o][kk]; xi = Fi[o][kk]; }
                #pragma unroll
                for (int c = 0; c < 16; ++c) {
                    const float cc = Cd[o * 16 + c];
                    xr = fmaf(cc, Xr[c][kk], xr);
                    xi = fmaf(cc, Xi[c][kk], xi);
                }
                if (kk == 0) xr += conv_b[d * 16 + o];
                xnr[k] = xr; xni[k] = xi;
            }
        }
        __syncthreads();
        if (d < 2) {
            #pragma unroll
            for (int k = 0; k < 4; ++k) {
                const int idx = tid + k * 256;
                const int o = idx >> 6, kk = idx & 63;
                Xr[o][kk] = xnr[k]; Xi[o][kk] = xni[k];
            }
            __syncthreads();
        }
    }

    // ---- epilogue: AH[hd][ky][kx] = c_ky * sum_c fc1[c,hd] * A[c][kx*8+ky] ----
    // n = tid + j*256 -> hd = n>>6 is wave-uniform (hd = j*4 + wave) -> s_load fc1.
    #pragma unroll
    for (int j = 0; j < 16; ++j) {
        const int n = tid + j * 256;                  // n = hd*64 + ky*8 + kx
        const int hd = n >> 6, ky = (n >> 3) & 7, kx = n & 7;
        const int kk = kx * 8 + ky;
        float ar = 0.f, ai = 0.f;
        #pragma unroll
        for (int c = 0; c < 16; ++c) {
            const float f = fc1_w[c * 64 + hd];       // wave-uniform -> s_load
            ar = fmaf(f, Ar[c][kk], ar);
            ai = fmaf(f, Ai[c][kk], ai);
        }
        const float ck = (ky == 0) ? 1.f : 2.f;       // Hermitian doubling (W axis)
        *(float2*)(AH + ((size_t)b * 4096 + n) * 2) = make_float2(ck * ar, ck * ai);
    }
    if (b == 0 && tid < NHID) {
        float g = 0.f, K = fc1_b[tid];
        #pragma unroll
        for (int c = 0; c < 16; ++c) {
            g = fmaf(fc1_w[c * 64 + tid], dvec[c], g);
            K = fmaf(fc1_w[c * 64 + tid], evec[c], K);
        }
        gvec[tid] = g;
        Kvec[tid] = K;
    }
}

// ---------------------------------------------------------------------------
// k_head: the ONLY per-pixel kernel. One (b,row) per block, 2 px/thread.
// WH[hd,ky] = sum_kx AH[b,hd,ky,kx] e^{+i kx th_row}            (per row)
// s_hd(px)  = Kvec[hd] + gvec[hd]*x + Re sum_ky WH e^{i ky th_w}
// out = fc2_b + sum_hd relu(s_hd) * fc2_w[hd]
// ---------------------------------------------------------------------------
__global__ __launch_bounds__(256, 4) void k_head(
        const float* __restrict__ x, const float* __restrict__ AH,
        const float* __restrict__ gvec, const float* __restrict__ Kvec,
        const float* __restrict__ fc2_w, const float* __restrict__ fc2_b,
        const float* __restrict__ twd,
        float* __restrict__ out) {
    __shared__ float WHr[512];   // [hd*8 + ky]
    __shared__ float WHi[512];

    const int tid = threadIdx.x;
    const int b = blockIdx.x >> 9;
    const int row = blockIdx.x & 511;

    // ---- build WH: 512 complex outputs, 2 per thread ----
    const float* AHb = AH + (size_t)b * 8192;
    #pragma unroll
    for (int k = 0; k < 2; ++k) {
        const int idx = tid + k * 256;                // idx = hd*8 + ky
        float ahv[16];
        const float4* ap = (const float4*)(AHb + (size_t)idx * 16);
        *(float4*)(&ahv[0])  = ap[0];
        *(float4*)(&ahv[4])  = ap[1];
        *(float4*)(&ahv[8])  = ap[2];
        *(float4*)(&ahv[12]) = ap[3];
        float wr = 0.f, wi = 0.f;
        #pragma unroll
        for (int kx = 0; kx < 8; ++kx) {
            const float tc = twd[(row * 8 + kx) * 2];       // uniform -> s_load
            const float ts = twd[(row * 8 + kx) * 2 + 1];
            const float ar = ahv[kx * 2], ai = ahv[kx * 2 + 1];
            wr += ar * tc - ai * ts;
            wi += ar * ts + ai * tc;
        }
        WHr[idx] = wr;
        WHi[idx] = wi;
    }

    const float* xrp = x + ((size_t)b * NH + row) * NW;
    const float xa = xrp[tid], xb = xrp[tid + 256];

    // per-pixel twiddles e^{+i ky th_w}, w = tid (w+256 via parity)
    float cta[8], sta[8];
    {
        const float4* q = (const float4*)(twd + (size_t)tid * 16);
        const float4 q0 = q[0], q1 = q[1], q2 = q[2], q3 = q[3];
        cta[0] = q0.x; sta[0] = q0.y; cta[1] = q0.z; sta[1] = q0.w;
        cta[2] = q1.x; sta[2] = q1.y; cta[3] = q1.z; sta[3] = q1.w;
        cta[4] = q2.x; sta[4] = q2.y; cta[5] = q2.z; sta[5] = q2.w;
        cta[6] = q3.x; sta[6] = q3.y; cta[7] = q3.z; sta[7] = q3.w;
    }
    __syncthreads();

    float aa = fc2_b[0], ab = aa;
    #pragma unroll 8
    for (int hd = 0; hd < NHID; ++hd) {
        const float4* r4 = (const float4*)(&WHr[hd * 8]);
        const float4 r0 = r4[0], r1 = r4[1];
        const float4* i4 = (const float4*)(&WHi[hd * 8]);
        const float4 i0 = i4[0], i1 = i4[1];
        // even ky (0,2,4,6): sta[0]=0 exactly -> skip imag term at ky=0
        float er = r0.x;                              // cta[0]=1
        er = fmaf(r0.z, cta[2], er); er = fmaf(-i0.z, sta[2], er);
        er = fmaf(r1.x, cta[4], er); er = fmaf(-i1.x, sta[4], er);
        er = fmaf(r1.z, cta[6], er); er = fmaf(-i1.z, sta[6], er);
        // odd ky (1,3,5,7)
        float od = r0.y * cta[1];
        od = fmaf(-i0.y, sta[1], od);
        od = fmaf(r0.w, cta[3], od); od = fmaf(-i0.w, sta[3], od);
        od = fmaf(r1.y, cta[5], od); od = fmaf(-i1.y, sta[5], od);
        od = fmaf(r1.w, cta[7], od); od = fmaf(-i1.w, sta[7], od);

        const float gh = gvec[hd], Kh = Kvec[hd];     // uniform -> s_load
        const float sa = (er + od) + fmaf(gh, xa, Kh);
        const float sb = (er - od) + fmaf(gh, xb, Kh);
        const float w2 = fc2_w[hd];
        aa = fmaf(fmaxf(sa, 0.f), w2, aa);
        ab = fmaf(fmaxf(sb, 0.f), w2, ab);
    }
    float* op = out + ((size_t)b * NH + row) * NW;
    op[tid] = aa;
    op[tid + 256] = ab;
}

// ---------------------------------------------------------------------------
extern "C" void kernel_launch(void* const* d_in, const int* in_sizes, int n_in,
                              void* d_out, int out_size, void* d_ws, size_t ws_size,
                              hipStream_t stream) {
    const float* x       = (const float*)d_in[0];
    const float* fc0_w   = (const float*)d_in[1];
    const float* fc0_b   = (const float*)d_in[2];
    const float* spec_wr = (const float*)d_in[3];
    const float* spec_wi = (const float*)d_in[4];
    const float* conv_w  = (const float*)d_in[5];
    const float* conv_b  = (const float*)d_in[6];
    const float* fc1_w   = (const float*)d_in[7];
    const float* fc1_b   = (const float*)d_in[8];
    const float* fc2_w   = (const float*)d_in[9];
    const float* fc2_b   = (const float*)d_in[10];
    float* out = (float*)d_out;

    char* ws = (char*)d_ws;
    size_t off = 0;
    float* G    = (float*)(ws + off); off += (size_t)NB * NC * NH * NM * 2 * 4;  // 4 MB
    float* Xft  = (float*)(ws + off); off += (size_t)NB * NC * NM * NM * 2 * 4;  // 64 KB
    float* AH   = (float*)(ws + off); off += (size_t)NB * NHID * NM * NM * 2 * 4;// 256 KB
    float* twd  = (float*)(ws + off); off += (size_t)NH * NM * 2 * 4;            // 32 KB
    float* P0   = (float*)(ws + off); off += 256 * 4;
    float* dvec = (float*)(ws + off); off += 16 * 4;
    float* evec = (float*)(ws + off); off += 16 * 4;
    float* gvec = (float*)(ws + off); off += NHID * 4;
    float* Kvec = (float*)(ws + off); off += NHID * 4;

    k_twprep<<<17, 256, 0, stream>>>(conv_w, conv_b, fc0_w, fc0_b, twd, P0, dvec, evec);
    k_g0<<<NB * NH, 256, 0, stream>>>(x, fc0_w, fc0_b, twd, G);
    k_B<<<NB * NC * NM, 256, 0, stream>>>(G, twd, Xft);
    k_modes<<<NB, 256, 0, stream>>>(Xft, spec_wr, spec_wi, conv_w, conv_b, P0,
                                    fc1_w, fc1_b, dvec, evec, AH, gvec, Kvec);
    k_head<<<NB * NH, 256, 0, stream>>>(x, AH, gvec, Kvec,
                                        fc2_w, fc2_b, twd, out);
}

// Round 6
// 153.180 us; speedup vs baseline: 2.7485x; 1.3383x over previous
//
#include <hip/hip_runtime.h>
#include <math.h>

#define NB 8
#define NC 16
#define NH 512
#define NW 512
#define NM 8
#define NHID 64
#define NDEPTH 3

// 2*pi/512
#define ANG512 0.01227184630308513f
// per-depth stride of spec_wr/spec_wi in floats: 16*16*8*8
#define SPEC_D 16384

// ---------------------------------------------------------------------------
// k_twprep: blocks 0..15 build the exact twiddle table
//   twd[(w*8+k)*2 + {0,1}] = cos/sin(ANG*w*k)  (angle reduced mod 512)
// block 16: P0 = C2*C1; dvec = P0*C0*fc0_w; evec = P0*(C0*fc0_b+cb0)+C2*cb1+cb2;
//           gvec = fc1^T dvec; Kvec = fc1_b + fc1^T evec.
// ---------------------------------------------------------------------------
__global__ __launch_bounds__(256) void k_twprep(
        const float* __restrict__ conv_w, const float* __restrict__ conv_b,
        const float* __restrict__ fc0_w, const float* __restrict__ fc0_b,
        const float* __restrict__ fc1_w, const float* __restrict__ fc1_b,
        float* __restrict__ twd, float* __restrict__ P0,
        float* __restrict__ gvec, float* __restrict__ Kvec) {
    if (blockIdx.x < 16) {
        const int idx = blockIdx.x * 256 + threadIdx.x;   // 0..4095 = w*8+k
        const int w = idx >> 3, k = idx & 7;
        const float ang = ANG512 * (float)((w * k) & 511);
        twd[idx * 2]     = cosf(ang);
        twd[idx * 2 + 1] = sinf(ang);
        return;
    }
    __shared__ float P_s[256];
    __shared__ float u_s[16];   // C0*fc0_w
    __shared__ float v_s[16];   // C0*fc0_b
    __shared__ float d_s[16];
    __shared__ float e_s[16];
    const int t = threadIdx.x;
    const float* C0 = conv_w;
    const float* C1 = conv_w + 256;
    const float* C2 = conv_w + 512;
    {
        const int o = t >> 4, c = t & 15;
        float s = 0.f;
        for (int k = 0; k < 16; ++k) s += C2[o * 16 + k] * C1[k * 16 + c];
        P_s[t] = s;
        P0[t] = s;
    }
    if (t < 16) {
        float s = 0.f, sb = 0.f;
        for (int c = 0; c < 16; ++c) {
            s  += C0[t * 16 + c] * fc0_w[c];
            sb += C0[t * 16 + c] * fc0_b[c];
        }
        u_s[t] = s;
        v_s[t] = sb;
    }
    __syncthreads();
    if (t < 16) {
        float dv = 0.f, ev = conv_b[32 + t];   // cb2[t]
        for (int k = 0; k < 16; ++k) {
            dv += P_s[t * 16 + k] * u_s[k];
            ev += P_s[t * 16 + k] * (v_s[k] + conv_b[k]);      // + P0*(C0*fc0_b + cb0)
            ev += C2[t * 16 + k] * conv_b[16 + k];             // + C2*cb1
        }
        d_s[t] = dv;
        e_s[t] = ev;
    }
    __syncthreads();
    if (t < NHID) {
        float g = 0.f, K = fc1_b[t];
        for (int c = 0; c < 16; ++c) {
            g = fmaf(fc1_w[c * 64 + t], d_s[c], g);
            K = fmaf(fc1_w[c * 64 + t], e_s[c], K);
        }
        gvec[t] = g;
        Kvec[t] = K;
    }
}

// ---------------------------------------------------------------------------
// block-wide reduction of 16 floats across 256 threads (4 waves).
// ---------------------------------------------------------------------------
__device__ __forceinline__ void block_reduce16(float* v, float* lds, int tid) {
    #pragma unroll
    for (int off = 32; off > 0; off >>= 1) {
        #pragma unroll
        for (int k = 0; k < 16; ++k) v[k] += __shfl_down(v[k], off);
    }
    const int wave = tid >> 6;
    if ((tid & 63) == 0) {
        #pragma unroll
        for (int k = 0; k < 16; ++k) lds[wave * 16 + k] = v[k];
    }
    __syncthreads();
    if (tid < 16) {
        lds[tid] = lds[tid] + lds[16 + tid] + lds[32 + tid] + lds[48 + tid];
    }
    __syncthreads();
}

// ---------------------------------------------------------------------------
// k_r1: row-DFT of x, NO channel dimension (fc0 is rank-1, folded later).
// R[b,row,ky] = sum_w x[b,0,row,w] * e^{-2pi i ky w/512}   (interleaved re/im)
// ---------------------------------------------------------------------------
__global__ __launch_bounds__(256) void k_r1(const float* __restrict__ x,
        const float* __restrict__ twd, float* __restrict__ R) {
    __shared__ float red[64];
    const int tid = threadIdx.x;
    const int b = blockIdx.x >> 9;
    const int row = blockIdx.x & 511;
    const float* xr = x + ((size_t)b * NH + row) * NW;

    float p[16];
    #pragma unroll
    for (int k = 0; k < 16; ++k) p[k] = 0.f;

    #pragma unroll
    for (int px = 0; px < 2; ++px) {
        const int w = tid + px * 256;
        const float v = xr[w];
        const float4* q = (const float4*)(twd + (size_t)w * 16);
        const float4 q0 = q[0], q1 = q[1], q2 = q[2], q3 = q[3];
        p[0] += v;
        p[1] = fmaf(v, q0.z, p[1]);  p[9]  = fmaf(-v, q0.w, p[9]);
        p[2] = fmaf(v, q1.x, p[2]);  p[10] = fmaf(-v, q1.y, p[10]);
        p[3] = fmaf(v, q1.z, p[3]);  p[11] = fmaf(-v, q1.w, p[11]);
        p[4] = fmaf(v, q2.x, p[4]);  p[12] = fmaf(-v, q2.y, p[12]);
        p[5] = fmaf(v, q2.z, p[5]);  p[13] = fmaf(-v, q2.w, p[13]);
        p[6] = fmaf(v, q3.x, p[6]);  p[14] = fmaf(-v, q3.y, p[14]);
        p[7] = fmaf(v, q3.z, p[7]);  p[15] = fmaf(-v, q3.w, p[15]);
    }
    block_reduce16(p, red, tid);
    if (tid < 16) {
        // interleave: q even -> re=red[q>>1], q odd -> im=red[8+(q>>1)]
        const float val = (tid & 1) ? red[8 + (tid >> 1)] : red[tid >> 1];
        R[((size_t)(b * NH + row)) * 16 + tid] = val;
    }
}

// ---------------------------------------------------------------------------
// k_modes2: grid (b,kx) = 64 blocks. Per block:
//  phase 0: stage all 3 layers' spectral weights for this kx into LDS
//  phase 1: col-DFT: X2d[ky] = sum_row R[b,row,ky] e^{-2pi i kx row/512}
//  phase 2 (tid<128, thread=(o,ky)):
//    X0[o,ky] = fc0_w[o]*X2d[ky]/HW + fc0_b[o]*(kx==0&&ky==0)
//    for d: F = X·w_d ; A += P_d F ; X = F̃ + C_d X + cb_d δ
//      F̃: ky=0 col: kx==0 -> (ReF,0); kx>0 -> F/2
//  phase 3: AH[b,hd,ky,kx] = c_ky * sum_c fc1[c,hd] A[c,ky]
// ---------------------------------------------------------------------------
__global__ __launch_bounds__(256) void k_modes2(
        const float* __restrict__ R, const float* __restrict__ twd,
        const float* __restrict__ spec_wr, const float* __restrict__ spec_wi,
        const float* __restrict__ conv_w, const float* __restrict__ conv_b,
        const float* __restrict__ P0g,
        const float* __restrict__ fc0_w, const float* __restrict__ fc0_b,
        const float* __restrict__ fc1_w,
        float* __restrict__ AH) {
    __shared__ float Wr_s[3][16][16][8];   // 24 KB
    __shared__ float Wi_s[3][16][16][8];   // 24 KB
    __shared__ float red[64];
    __shared__ float Xr_s[16][8], Xi_s[16][8];
    __shared__ float Fr_s[16][8], Fi_s[16][8];
    __shared__ float Ar_s[16][8], Ai_s[16][8];
    __shared__ float Pm_s[2][256];
    __shared__ float C_s[2][256];
    __shared__ float cb_s[32];
    __shared__ float fc1_s[1024];

    const int tid = threadIdx.x;
    const int b = blockIdx.x >> 3;
    const int kx = blockIdx.x & 7;

    // ---- phase 0: stage weights + small matrices ----
    {
        const int i = tid >> 4, o = tid & 15;
        #pragma unroll
        for (int d = 0; d < NDEPTH; ++d) {
            const size_t base = (size_t)d * SPEC_D + ((size_t)(i * 16 + o) * 64 + kx * 8);
            const float4* pr = (const float4*)(spec_wr + base);
            const float4* pi = (const float4*)(spec_wi + base);
            *(float4*)(&Wr_s[d][i][o][0]) = pr[0];
            *(float4*)(&Wr_s[d][i][o][4]) = pr[1];
            *(float4*)(&Wi_s[d][i][o][0]) = pi[0];
            *(float4*)(&Wi_s[d][i][o][4]) = pi[1];
        }
    }
    Pm_s[0][tid] = P0g[tid];
    Pm_s[1][tid] = conv_w[512 + tid];   // C2
    C_s[0][tid]  = conv_w[tid];         // C0
    C_s[1][tid]  = conv_w[256 + tid];   // C1
    if (tid < 32) cb_s[tid] = conv_b[tid];
    #pragma unroll
    for (int k = 0; k < 4; ++k) fc1_s[tid + k * 256] = fc1_w[tid + k * 256];

    // ---- phase 1: col-DFT of R ----
    float p[16];
    #pragma unroll
    for (int k = 0; k < 16; ++k) p[k] = 0.f;
    #pragma unroll
    for (int r2 = 0; r2 < 2; ++r2) {
        const int row = tid + r2 * 256;
        const float4* rp = (const float4*)(R + ((size_t)(b * NH + row)) * 16);
        const float4 g0 = rp[0], g1 = rp[1], g2 = rp[2], g3 = rp[3];
        const int m = (kx * row) & 511;
        const float2 t = *(const float2*)(twd + (size_t)(m * 8 + 1) * 2);
        const float tc = t.x, ts = t.y;   // e^{-i th m} = (tc, -ts)
        // (a+ib)(tc - i ts) = (a tc + b ts) + i (b tc - a ts)
        p[0] += g0.x * tc + g0.y * ts;  p[8]  += g0.y * tc - g0.x * ts;
        p[1] += g0.z * tc + g0.w * ts;  p[9]  += g0.w * tc - g0.z * ts;
        p[2] += g1.x * tc + g1.y * ts;  p[10] += g1.y * tc - g1.x * ts;
        p[3] += g1.z * tc + g1.w * ts;  p[11] += g1.w * tc - g1.z * ts;
        p[4] += g2.x * tc + g2.y * ts;  p[12] += g2.y * tc - g2.x * ts;
        p[5] += g2.z * tc + g2.w * ts;  p[13] += g2.w * tc - g2.z * ts;
        p[6] += g3.x * tc + g3.y * ts;  p[14] += g3.y * tc - g3.x * ts;
        p[7] += g3.z * tc + g3.w * ts;  p[15] += g3.w * tc - g3.z * ts;
    }
    block_reduce16(p, red, tid);   // trailing syncthreads covers staging too

    // ---- phase 2: 3-layer recurrence (thread = (o,ky), tid<128) ----
    const bool act = (tid < 128);
    const int o = tid >> 3, ky = tid & 7;
    if (act) {
        const float inv = 1.f / (512.f * 512.f);
        float xr = fc0_w[o] * red[ky] * inv;
        float xi = fc0_w[o] * red[8 + ky] * inv;
        if (kx == 0 && ky == 0) xr += fc0_b[o];
        Xr_s[o][ky] = xr; Xi_s[o][ky] = xi;
        Ar_s[o][ky] = 0.f; Ai_s[o][ky] = 0.f;
    }
    __syncthreads();

    for (int d = 0; d < NDEPTH; ++d) {
        float fr = 0.f, fi = 0.f;
        if (act) {
            #pragma unroll
            for (int i = 0; i < 16; ++i) {
                const float wre = Wr_s[d][i][o][ky];
                const float wim = Wi_s[d][i][o][ky];
                const float xr = Xr_s[i][ky], xi = Xi_s[i][ky];
                fr += xr * wre - xi * wim;
                fi += xr * wim + xi * wre;
            }
            Fr_s[o][ky] = fr; Fi_s[o][ky] = fi;
        }
        __syncthreads();

        float xnr = 0.f, xni = 0.f;
        if (act) {
            float ar, ai;
            if (d == 2) {
                ar = Fr_s[o][ky]; ai = Fi_s[o][ky];
            } else {
                ar = 0.f; ai = 0.f;
                #pragma unroll
                for (int c = 0; c < 16; ++c) {
                    const float pv = Pm_s[d][o * 16 + c];
                    ar = fmaf(pv, Fr_s[c][ky], ar);
                    ai = fmaf(pv, Fi_s[c][ky], ai);
                }
            }
            Ar_s[o][ky] += ar; Ai_s[o][ky] += ai;

            if (d < 2) {
                if (ky == 0) {
                    if (kx == 0) { xnr = Fr_s[o][0]; xni = 0.f; }
                    else         { xnr = 0.5f * Fr_s[o][0]; xni = 0.5f * Fi_s[o][0]; }
                } else { xnr = Fr_s[o][ky]; xni = Fi_s[o][ky]; }
                #pragma unroll
                for (int c = 0; c < 16; ++c) {
                    const float cc = C_s[d][o * 16 + c];
                    xnr = fmaf(cc, Xr_s[c][ky], xnr);
                    xni = fmaf(cc, Xi_s[c][ky], xni);
                }
                if (kx == 0 && ky == 0) xnr += cb_s[d * 16 + o];
            }
        }
        __syncthreads();   // all X reads done before overwrite
        if (act && d < 2) { Xr_s[o][ky] = xnr; Xi_s[o][ky] = xni; }
        __syncthreads();
    }

    // ---- phase 3: fold fc1 -> AH[b][hd][ky][kx] ----
    #pragma unroll
    for (int k2 = 0; k2 < 2; ++k2) {
        const int idx = tid + k2 * 256;        // hd*8 + ky2
        const int hd = idx >> 3, ky2 = idx & 7;
        float ar = 0.f, ai = 0.f;
        #pragma unroll
        for (int c = 0; c < 16; ++c) {
            const float f = fc1_s[c * 64 + hd];
            ar = fmaf(f, Ar_s[c][ky2], ar);
            ai = fmaf(f, Ai_s[c][ky2], ai);
        }
        const float ck = (ky2 == 0) ? 1.f : 2.f;    // Hermitian doubling (W axis)
        const size_t off = ((((size_t)(b * 64 + hd)) * 8 + ky2) * 8 + kx) * 2;
        AH[off]     = ck * ar;
        AH[off + 1] = ck * ai;
    }
}

// ---------------------------------------------------------------------------
// k_head: the ONLY per-pixel kernel. One (b,row) per block, 2 px/thread.
// WH[hd,ky] = sum_kx AH[b,hd,ky,kx] e^{+i kx th_row}            (per row)
// s_hd(px)  = Kvec[hd] + gvec[hd]*x + Re sum_ky WH e^{i ky th_w}
// out = fc2_b + sum_hd relu(s_hd) * fc2_w[hd]
// ---------------------------------------------------------------------------
__global__ __launch_bounds__(256, 8) void k_head(
        const float* __restrict__ x, const float* __restrict__ AH,
        const float* __restrict__ gvec, const float* __restrict__ Kvec,
        const float* __restrict__ fc2_w, const float* __restrict__ fc2_b,
        const float* __restrict__ twd,
        float* __restrict__ out) {
    __shared__ float WHr[512];   // [hd*8 + ky]
    __shared__ float WHi[512];

    const int tid = threadIdx.x;
    const int b = blockIdx.x >> 9;
    const int row = blockIdx.x & 511;

    // ---- build WH: 512 complex outputs, 2 per thread ----
    const float* AHb = AH + (size_t)b * 8192;
    #pragma unroll
    for (int k = 0; k < 2; ++k) {
        const int idx = tid + k * 256;                // idx = hd*8 + ky
        float ahv[16];
        const float4* ap = (const float4*)(AHb + (size_t)idx * 16);
        *(float4*)(&ahv[0])  = ap[0];
        *(float4*)(&ahv[4])  = ap[1];
        *(float4*)(&ahv[8])  = ap[2];
        *(float4*)(&ahv[12]) = ap[3];
        float wr = 0.f, wi = 0.f;
        #pragma unroll
        for (int kx = 0; kx < 8; ++kx) {
            const float tc = twd[(row * 8 + kx) * 2];       // uniform -> s_load
            const float ts = twd[(row * 8 + kx) * 2 + 1];
            const float ar = ahv[kx * 2], ai = ahv[kx * 2 + 1];
            wr += ar * tc - ai * ts;
            wi += ar * ts + ai * tc;
        }
        WHr[idx] = wr;
        WHi[idx] = wi;
    }

    const float* xrp = x + ((size_t)b * NH + row) * NW;
    const float xa = xrp[tid], xb = xrp[tid + 256];

    // per-pixel twiddles e^{+i ky th_w}, w = tid (w+256 via parity)
    float cta[8], sta[8];
    {
        const float4* q = (const float4*)(twd + (size_t)tid * 16);
        const float4 q0 = q[0], q1 = q[1], q2 = q[2], q3 = q[3];
        cta[0] = q0.x; sta[0] = q0.y; cta[1] = q0.z; sta[1] = q0.w;
        cta[2] = q1.x; sta[2] = q1.y; cta[3] = q1.z; sta[3] = q1.w;
        cta[4] = q2.x; sta[4] = q2.y; cta[5] = q2.z; sta[5] = q2.w;
        cta[6] = q3.x; sta[6] = q3.y; cta[7] = q3.z; sta[7] = q3.w;
    }
    __syncthreads();

    float aa = fc2_b[0], ab = aa;
    #pragma unroll 8
    for (int hd = 0; hd < NHID; ++hd) {
        const float4* r4 = (const float4*)(&WHr[hd * 8]);
        const float4 r0 = r4[0], r1 = r4[1];
        const float4* i4 = (const float4*)(&WHi[hd * 8]);
        const float4 i0 = i4[0], i1 = i4[1];
        // even ky (0,2,4,6): sta[0]=0 exactly -> skip imag term at ky=0
        float er = r0.x;                              // cta[0]=1
        er = fmaf(r0.z, cta[2], er); er = fmaf(-i0.z, sta[2], er);
        er = fmaf(r1.x, cta[4], er); er = fmaf(-i1.x, sta[4], er);
        er = fmaf(r1.z, cta[6], er); er = fmaf(-i1.z, sta[6], er);
        // odd ky (1,3,5,7)
        float od = r0.y * cta[1];
        od = fmaf(-i0.y, sta[1], od);
        od = fmaf(r0.w, cta[3], od); od = fmaf(-i0.w, sta[3], od);
        od = fmaf(r1.y, cta[5], od); od = fmaf(-i1.y, sta[5], od);
        od = fmaf(r1.w, cta[7], od); od = fmaf(-i1.w, sta[7], od);

        const float gh = gvec[hd], Kh = Kvec[hd];     // uniform -> s_load
        const float sa = (er + od) + fmaf(gh, xa, Kh);
        const float sb = (er - od) + fmaf(gh, xb, Kh);
        const float w2 = fc2_w[hd];
        aa = fmaf(fmaxf(sa, 0.f), w2, aa);
        ab = fmaf(fmaxf(sb, 0.f), w2, ab);
    }
    float* op = out + ((size_t)b * NH + row) * NW;
    op[tid] = aa;
    op[tid + 256] = ab;
}

// ---------------------------------------------------------------------------
extern "C" void kernel_launch(void* const* d_in, const int* in_sizes, int n_in,
                              void* d_out, int out_size, void* d_ws, size_t ws_size,
                              hipStream_t stream) {
    const float* x       = (const float*)d_in[0];
    const float* fc0_w   = (const float*)d_in[1];
    const float* fc0_b   = (const float*)d_in[2];
    const float* spec_wr = (const float*)d_in[3];
    const float* spec_wi = (const float*)d_in[4];
    const float* conv_w  = (const float*)d_in[5];
    const float* conv_b  = (const float*)d_in[6];
    const float* fc1_w   = (const float*)d_in[7];
    const float* fc1_b   = (const float*)d_in[8];
    const float* fc2_w   = (const float*)d_in[9];
    const float* fc2_b   = (const float*)d_in[10];
    float* out = (float*)d_out;

    char* ws = (char*)d_ws;
    size_t off = 0;
    float* R    = (float*)(ws + off); off += (size_t)NB * NH * NM * 2 * 4;        // 256 KB
    float* AH   = (float*)(ws + off); off += (size_t)NB * NHID * NM * NM * 2 * 4; // 256 KB
    float* twd  = (float*)(ws + off); off += (size_t)NH * NM * 2 * 4;             // 32 KB
    float* P0   = (float*)(ws + off); off += 256 * 4;
    float* gvec = (float*)(ws + off); off += NHID * 4;
    float* Kvec = (float*)(ws + off); off += NHID * 4;

    k_twprep<<<17, 256, 0, stream>>>(conv_w, conv_b, fc0_w, fc0_b, fc1_w, fc1_b,
                                     twd, P0, gvec, Kvec);
    k_r1<<<NB * NH, 256, 0, stream>>>(x, twd, R);
    k_modes2<<<NB * NM, 256, 0, stream>>>(R, twd, spec_wr, spec_wi, conv_w, conv_b,
                                          P0, fc0_w, fc0_b, fc1_w, AH);
    k_head<<<NB * NH, 256, 0, stream>>>(x, AH, gvec, Kvec, fc2_w, fc2_b, twd, out);
}

// Round 8
// 151.708 us; speedup vs baseline: 2.7751x; 1.0097x over previous
//
#include <hip/hip_runtime.h>
#include <math.h>

#define NB 8
#define NH 512
#define NW 512
#define ANG512 0.01227184630308513f
#define SPEC_D 16384   // per-depth stride of spec_wr/spec_wi (16*16*8*8)

// ---------------------------------------------------------------------------
// transpose-reduce: 256 threads each hold p[16]; result (sum over threads)
// lands in dst[0..15]. tb must hold 128*17 floats.
// ---------------------------------------------------------------------------
__device__ __forceinline__ void treduce16(float* p, float* tb, float* dst, int tid) {
    #pragma unroll
    for (int j = 0; j < 16; ++j) p[j] += __shfl_xor(p[j], 1);
    if (!(tid & 1)) {
        const int s = tid >> 1;               // 0..127
        #pragma unroll
        for (int j = 0; j < 16; ++j) tb[s * 17 + j] = p[j];
    }
    __syncthreads();
    {
        const int q = tid >> 4, g = tid & 15;
        float v = 0.f;
        #pragma unroll
        for (int j = 0; j < 8; ++j) v += tb[(g + 16 * j) * 17 + q];
        #pragma unroll
        for (int m = 1; m < 16; m <<= 1) v += __shfl_xor(v, m, 16);
        if (g == 0) dst[q] = v;
    }
    __syncthreads();
}

// ---------------------------------------------------------------------------
// k_rowdft: one (b,row) per block.
// R[b,row, 0..7]=Re, [8..15]=Im of sum_w x[b,0,row,w] e^{-2pi i ky w/512}
// ---------------------------------------------------------------------------
__global__ __launch_bounds__(256) void k_rowdft(const float* __restrict__ x,
                                                float* __restrict__ R) {
    __shared__ float tb[128 * 17];
    __shared__ float red[16];
    const int tid = threadIdx.x;
    const int b = blockIdx.x >> 9;
    const int row = blockIdx.x & 511;
    const float* xr = x + ((size_t)(b * NH + row)) * NW;
    const float xa = xr[tid], xb = xr[tid + 256];
    const float a = xa + xb, d = xa - xb;   // parity: tw(w+256)=(-1)^k tw(w)

    float p[16];
    float c1, s1;
    __sincosf(ANG512 * (float)tid, &s1, &c1);
    p[0] = a;      p[8] = 0.f;
    p[1] = d * c1; p[9] = -d * s1;
    {
        const float c2k = 2.f * c1;
        float ckm = 1.f, skm = 0.f, ck = c1, sk = s1;
        #pragma unroll
        for (int k = 2; k < 8; ++k) {
            const float cn = fmaf(c2k, ck, -ckm);
            const float sn = fmaf(c2k, sk, -skm);
            ckm = ck; skm = sk; ck = cn; sk = sn;
            const float v = (k & 1) ? d : a;
            p[k] = v * ck;
            p[8 + k] = -v * sk;
        }
    }
    treduce16(p, tb, red, tid);
    if (tid < 16) R[((size_t)(b * NH + row)) * 16 + tid] = red[tid];
}

// ---------------------------------------------------------------------------
// k_modes: grid (b,kx) = 64 blocks.
//  col-DFT of R -> X2d[ky]; X0 = fc0-fold; 3-layer mode recurrence;
//  AH[b,hd,ky,kx] = c_ky * sum_c fc1[c,hd] A[c,ky].
//  block 0 additionally computes gvec/Kvec.
// ---------------------------------------------------------------------------
__global__ __launch_bounds__(256) void k_modes(
        const float* __restrict__ R,
        const float* __restrict__ spec_wr, const float* __restrict__ spec_wi,
        const float* __restrict__ conv_w, const float* __restrict__ conv_b,
        const float* __restrict__ fc0_w, const float* __restrict__ fc0_b,
        const float* __restrict__ fc1_w, const float* __restrict__ fc1_b,
        float* __restrict__ AH, float* __restrict__ gvec, float* __restrict__ Kvec) {
    __shared__ float Wr_s[3][16][16][8];   // 24 KB
    __shared__ float Wi_s[3][16][16][8];   // 24 KB
    __shared__ float tb[128 * 17];
    __shared__ float X2[16];
    __shared__ float Xr[16][8], Xi[16][8];
    __shared__ float Fr[16][8], Fi[16][8];
    __shared__ float Ar[16][8], Ai[16][8];
    __shared__ float Pm[2][256];           // [0]=C2*C1, [1]=C2
    __shared__ float fc1_s[1024];
    __shared__ float ps[64];               // prep scratch (block 0)

    const int tid = threadIdx.x;
    const int bb = blockIdx.x >> 3;
    const int kx = blockIdx.x & 7;

    // ---- stage spectral weights for this kx ----
    {
        const int i = tid >> 4, o = tid & 15;
        #pragma unroll
        for (int d = 0; d < 3; ++d) {
            const size_t base = (size_t)d * SPEC_D + ((size_t)(i * 16 + o) * 64 + kx * 8);
            const float4* pr = (const float4*)(spec_wr + base);
            const float4* pi = (const float4*)(spec_wi + base);
            *(float4*)(&Wr_s[d][i][o][0]) = pr[0];
            *(float4*)(&Wr_s[d][i][o][4]) = pr[1];
            *(float4*)(&Wi_s[d][i][o][0]) = pi[0];
            *(float4*)(&Wi_s[d][i][o][4]) = pi[1];
        }
    }
    // ---- Pm[0] = C2*C1 (in-block), Pm[1] = C2, stage fc1 ----
    {
        const int o = tid >> 4, c = tid & 15;
        float s = 0.f;
        for (int k = 0; k < 16; ++k)
            s += conv_w[512 + o * 16 + k] * conv_w[256 + k * 16 + c];
        Pm[0][tid] = s;
    }
    Pm[1][tid] = conv_w[512 + tid];
    #pragma unroll
    for (int k = 0; k < 4; ++k) fc1_s[tid + k * 256] = fc1_w[tid + k * 256];

    // ---- col-DFT: X2d[ky] = sum_row R[bb,row,ky] e^{-2pi i kx row/512} ----
    float p[16];
    #pragma unroll
    for (int j = 0; j < 16; ++j) p[j] = 0.f;
    #pragma unroll
    for (int r2 = 0; r2 < 2; ++r2) {
        const int row = tid + r2 * 256;
        const float4* rp4 = (const float4*)(R + ((size_t)(bb * NH + row)) * 16);
        const float4 q0 = rp4[0], q1 = rp4[1], q2 = rp4[2], q3 = rp4[3];
        const float re[8] = {q0.x, q0.y, q0.z, q0.w, q1.x, q1.y, q1.z, q1.w};
        const float im[8] = {q2.x, q2.y, q2.z, q2.w, q3.x, q3.y, q3.z, q3.w};
        const int m = (kx * row) & 511;
        float cm, sm;
        __sincosf(ANG512 * (float)m, &sm, &cm);   // e^{-i th m} = (cm, -sm)
        #pragma unroll
        for (int k = 0; k < 8; ++k) {
            p[k]     += re[k] * cm + im[k] * sm;
            p[8 + k] += im[k] * cm - re[k] * sm;
        }
    }
    treduce16(p, tb, X2, tid);   // internal syncs also cover the staging above

    // ---- recurrence: thread = (o,ky), tid < 128 ----
    const bool act = (tid < 128);
    const int o = tid >> 3, ky = tid & 7;
    if (act) {
        const float inv = 1.f / (512.f * 512.f);
        float xr0 = fc0_w[o] * X2[ky] * inv;
        float xi0 = fc0_w[o] * X2[8 + ky] * inv;
        if (kx == 0 && ky == 0) xr0 += fc0_b[o];
        Xr[o][ky] = xr0; Xi[o][ky] = xi0;
        Ar[o][ky] = 0.f; Ai[o][ky] = 0.f;
    }
    __syncthreads();

    for (int dd = 0; dd < 3; ++dd) {
        if (act) {
            float fr = 0.f, fi = 0.f;
            #pragma unroll
            for (int i = 0; i < 16; ++i) {
                const float wre = Wr_s[dd][i][o][ky];
                const float wim = Wi_s[dd][i][o][ky];
                const float xr0 = Xr[i][ky], xi0 = Xi[i][ky];
                fr += xr0 * wre - xi0 * wim;
                fi += xr0 * wim + xi0 * wre;
            }
            Fr[o][ky] = fr; Fi[o][ky] = fi;
        }
        __syncthreads();
        float xnr = 0.f, xni = 0.f;
        if (act) {
            float ar, ai;
            if (dd == 2) {
                ar = Fr[o][ky]; ai = Fi[o][ky];
            } else {
                ar = 0.f; ai = 0.f;
                #pragma unroll
                for (int c = 0; c < 16; ++c) {
                    const float pv = Pm[dd][o * 16 + c];
                    ar = fmaf(pv, Fr[c][ky], ar);
                    ai = fmaf(pv, Fi[c][ky], ai);
                }
            }
            Ar[o][ky] += ar; Ai[o][ky] += ai;
            if (dd < 2) {
                const float fr0 = Fr[o][ky], fi0 = Fi[o][ky];
                if (ky == 0) {
                    if (kx == 0) { xnr = fr0; xni = 0.f; }
                    else         { xnr = 0.5f * fr0; xni = 0.5f * fi0; }
                } else { xnr = fr0; xni = fi0; }
                #pragma unroll
                for (int c = 0; c < 16; ++c) {
                    const float cc = conv_w[dd * 256 + o * 16 + c];
                    xnr = fmaf(cc, Xr[c][ky], xnr);
                    xni = fmaf(cc, Xi[c][ky], xni);
                }
                if (kx == 0 && ky == 0) xnr += conv_b[dd * 16 + o];
            }
        }
        __syncthreads();
        if (act && dd < 2) { Xr[o][ky] = xnr; Xi[o][ky] = xni; }
        __syncthreads();
    }

    // ---- fold fc1 -> AH[b,hd,ky,kx] (interleaved complex) ----
    #pragma unroll
    for (int k2 = 0; k2 < 2; ++k2) {
        const int idx = tid + k2 * 256;      // hd*8 + ky2
        const int hd = idx >> 3, ky2 = idx & 7;
        float ar = 0.f, ai = 0.f;
        #pragma unroll
        for (int c = 0; c < 16; ++c) {
            const float f = fc1_s[c * 64 + hd];
            ar = fmaf(f, Ar[c][ky2], ar);
            ai = fmaf(f, Ai[c][ky2], ai);
        }
        const float ck = (ky2 == 0) ? 1.f : 2.f;    // Hermitian doubling
        const size_t off = ((((size_t)(bb * 64 + hd)) * 8 + ky2) * 8 + kx) * 2;
        AH[off] = ck * ar;
        AH[off + 1] = ck * ai;
    }

    // ---- block 0: gvec = fc1^T(P0*C0*fc0_w); Kvec = fc1_b + fc1^T(evec) ----
    if (blockIdx.x == 0) {
        if (tid < 16) {
            float su = 0.f, sb = 0.f;
            for (int c = 0; c < 16; ++c) {
                su += conv_w[tid * 16 + c] * fc0_w[c];
                sb += conv_w[tid * 16 + c] * fc0_b[c];
            }
            ps[tid] = su; ps[16 + tid] = sb;
        }
        __syncthreads();
        if (tid < 16) {
            float dv = 0.f, ev = conv_b[32 + tid];
            for (int k = 0; k < 16; ++k) {
                dv += Pm[0][tid * 16 + k] * ps[k];
                ev += Pm[0][tid * 16 + k] * (ps[16 + k] + conv_b[k]);
                ev += conv_w[512 + tid * 16 + k] * conv_b[16 + k];
            }
            ps[32 + tid] = dv; ps[48 + tid] = ev;
        }
        __syncthreads();
        if (tid < 64) {
            float g = 0.f, K = fc1_b[tid];
            for (int c = 0; c < 16; ++c) {
                g = fmaf(fc1_w[c * 64 + tid], ps[32 + c], g);
                K = fmaf(fc1_w[c * 64 + tid], ps[48 + c], K);
            }
            gvec[tid] = g; Kvec[tid] = K;
        }
    }
}

// ---------------------------------------------------------------------------
// k_head: 2 rows per block, 4 px/thread via i^ky quarter-rotation.
// WH[hd,ky] = sum_kx AH e^{+i kx th_row}  (Kvec folded into ky=0 real)
// s_hd(w)   = Re sum_ky WH e^{+i ky th_w} + gvec[hd]*x
// out = fc2_b + sum_hd relu(s_hd) * fc2_w[hd]
// ---------------------------------------------------------------------------
__global__ __launch_bounds__(256, 4) void k_head(
        const float* __restrict__ x, const float* __restrict__ AH,
        const float* __restrict__ gvec, const float* __restrict__ Kvec,
        const float* __restrict__ fc2_w, const float* __restrict__ fc2_b,
        float* __restrict__ out) {
    __shared__ float WHr[2][512];
    __shared__ float WHi[2][512];

    const int tid = threadIdx.x;
    const int b = blockIdx.x >> 8;
    const int rp = blockIdx.x & 255;
    const int half = tid >> 7;
    const int row = rp * 2 + half;
    const int t7 = tid & 127;

    // ---- WH build (4 entries/thread for this thread's row) ----
    {
        float c1, s1;
        __sincosf(ANG512 * (float)row, &s1, &c1);
        float ctr[8], str[8];
        ctr[0] = 1.f; str[0] = 0.f; ctr[1] = c1; str[1] = s1;
        const float c2k = 2.f * c1;
        #pragma unroll
        for (int k = 2; k < 8; ++k) {
            ctr[k] = fmaf(c2k, ctr[k - 1], -ctr[k - 2]);
            str[k] = fmaf(c2k, str[k - 1], -str[k - 2]);
        }
        #pragma unroll
        for (int k2 = 0; k2 < 4; ++k2) {
            const int idx = t7 + k2 * 128;   // hd*8 + ky
            const int hd = idx >> 3, ky = idx & 7;
            const float4* ap = (const float4*)(AH + ((size_t)(b * 64 + hd) * 8 + ky) * 16);
            const float4 a0 = ap[0], a1 = ap[1], a2 = ap[2], a3 = ap[3];
            float wr = a0.x, wi = a0.y;      // kx=0
            wr = fmaf(a0.z, ctr[1], wr); wr = fmaf(-a0.w, str[1], wr);
            wi = fmaf(a0.z, str[1], wi); wi = fmaf(a0.w, ctr[1], wi);
            wr = fmaf(a1.x, ctr[2], wr); wr = fmaf(-a1.y, str[2], wr);
            wi = fmaf(a1.x, str[2], wi); wi = fmaf(a1.y, ctr[2], wi);
            wr = fmaf(a1.z, ctr[3], wr); wr = fmaf(-a1.w, str[3], wr);
            wi = fmaf(a1.z, str[3], wi); wi = fmaf(a1.w, ctr[3], wi);
            wr = fmaf(a2.x, ctr[4], wr); wr = fmaf(-a2.y, str[4], wr);
            wi = fmaf(a2.x, str[4], wi); wi = fmaf(a2.y, ctr[4], wi);
            wr = fmaf(a2.z, ctr[5], wr); wr = fmaf(-a2.w, str[5], wr);
            wi = fmaf(a2.z, str[5], wi); wi = fmaf(a2.w, ctr[5], wi);
            wr = fmaf(a3.x, ctr[6], wr); wr = fmaf(-a3.y, str[6], wr);
            wi = fmaf(a3.x, str[6], wi); wi = fmaf(a3.y, ctr[6], wi);
            wr = fmaf(a3.z, ctr[7], wr); wr = fmaf(-a3.w, str[7], wr);
            wi = fmaf(a3.z, str[7], wi); wi = fmaf(a3.w, ctr[7], wi);
            if (ky == 0) wr += Kvec[hd];
            WHr[half][idx] = wr;
            WHi[half][idx] = wi;
        }
    }
    __syncthreads();

    // ---- 4 px/thread: w0, w0+128, w0+256, w0+384 (i^ky rotation) ----
    {
        const int w0 = t7;
        const float* xp = x + ((size_t)(b * NH + row)) * NW + w0;
        const float x0 = xp[0], x1 = xp[128], x2 = xp[256], x3 = xp[384];
        float c1, s1;
        __sincosf(ANG512 * (float)w0, &s1, &c1);
        float ct[8], st[8];
        ct[0] = 1.f; st[0] = 0.f; ct[1] = c1; st[1] = s1;
        const float c2k = 2.f * c1;
        #pragma unroll
        for (int k = 2; k < 8; ++k) {
            ct[k] = fmaf(c2k, ct[k - 1], -ct[k - 2]);
            st[k] = fmaf(c2k, st[k - 1], -st[k - 2]);
        }
        const float* WR = &WHr[half][0];
        const float* WI = &WHi[half][0];
        const float fc2b = fc2_b[0];
        float acc0 = fc2b, acc1 = fc2b, acc2 = fc2b, acc3 = fc2b;
        #pragma unroll 4
        for (int hd = 0; hd < 64; ++hd) {
            const float4* r4 = (const float4*)(WR + hd * 8);
            const float4 wa = r4[0], wb = r4[1];
            const float4* i4 = (const float4*)(WI + hd * 8);
            const float4 va = i4[0], vb = i4[1];
            const float tr0 = wa.x;
            const float tr1 = wa.y * ct[1] - va.y * st[1];
            const float tr2 = wa.z * ct[2] - va.z * st[2];
            const float tr3 = wa.w * ct[3] - va.w * st[3];
            const float tr4 = wb.x * ct[4] - vb.x * st[4];
            const float tr5 = wb.y * ct[5] - vb.y * st[5];
            const float tr6 = wb.z * ct[6] - vb.z * st[6];
            const float tr7 = wb.w * ct[7] - vb.w * st[7];
            const float ti1 = wa.y * st[1] + va.y * ct[1];
            const float ti3 = wa.w * st[3] + va.w * ct[3];
            const float ti5 = wb.y * st[5] + vb.y * ct[5];
            const float ti7 = wb.w * st[7] + vb.w * ct[7];
            const float A0 = tr0 + tr4, A2 = tr2 + tr6;
            const float B13 = (tr1 + tr5) + (tr3 + tr7);
            const float U = (ti1 + ti5) - (ti3 + ti7);
            const float E = A0 + A2, D = A0 - A2;
            const float gh = gvec[hd];
            const float w2 = fc2_w[hd];
            const float s0 = E + B13 + gh * x0;
            const float s1p = D - U + gh * x1;
            const float s2p = E - B13 + gh * x2;
            const float s3p = D + U + gh * x3;
            acc0 = fmaf(fmaxf(s0, 0.f),  w2, acc0);
            acc1 = fmaf(fmaxf(s1p, 0.f), w2, acc1);
            acc2 = fmaf(fmaxf(s2p, 0.f), w2, acc2);
            acc3 = fmaf(fmaxf(s3p, 0.f), w2, acc3);
        }
        float* op = out + ((size_t)(b * NH + row)) * NW + w0;
        op[0] = acc0; op[128] = acc1; op[256] = acc2; op[384] = acc3;
    }
}

// ---------------------------------------------------------------------------
extern "C" void kernel_launch(void* const* d_in, const int* in_sizes, int n_in,
                              void* d_out, int out_size, void* d_ws, size_t ws_size,
                              hipStream_t stream) {
    const float* x       = (const float*)d_in[0];
    const float* fc0_w   = (const float*)d_in[1];
    const float* fc0_b   = (const float*)d_in[2];
    const float* spec_wr = (const float*)d_in[3];
    const float* spec_wi = (const float*)d_in[4];
    const float* conv_w  = (const float*)d_in[5];
    const float* conv_b  = (const float*)d_in[6];
    const float* fc1_w   = (const float*)d_in[7];
    const float* fc1_b   = (const float*)d_in[8];
    const float* fc2_w   = (const float*)d_in[9];
    const float* fc2_b   = (const float*)d_in[10];
    float* outp = (float*)d_out;

    char* ws = (char*)d_ws;
    float* R  = (float*)ws;                       // 8*512*16 floats = 256 KB
    float* AH = (float*)(ws + 262144);            // 8*64*64*2 floats = 256 KB
    float* gv = (float*)(ws + 524288);            // 64 floats
    float* Kv = (float*)(ws + 524288 + 256);      // 64 floats

    k_rowdft<<<NB * NH, 256, 0, stream>>>(x, R);
    k_modes<<<NB * 8, 256, 0, stream>>>(R, spec_wr, spec_wi, conv_w, conv_b,
                                        fc0_w, fc0_b, fc1_w, fc1_b, AH, gv, Kv);
    k_head<<<NB * 256, 256, 0, stream>>>(x, AH, gv, Kv, fc2_w, fc2_b, outp);
}

// Round 9
// 145.507 us; speedup vs baseline: 2.8934x; 1.0426x over previous
//
#include <hip/hip_runtime.h>
#include <math.h>

#define NB 8
#define NH 512
#define NW 512
#define ANG512 0.01227184630308513f
#define SPEC_D 16384   // per-depth stride of spec_wr/spec_wi (16*16*8*8)

// ---------------------------------------------------------------------------
// transpose-reduce: 256 threads each hold p[16]; result (sum over threads)
// lands in dst[0..15]. tb must hold 128*17 floats.
// ---------------------------------------------------------------------------
__device__ __forceinline__ void treduce16(float* p, float* tb, float* dst, int tid) {
    #pragma unroll
    for (int j = 0; j < 16; ++j) p[j] += __shfl_xor(p[j], 1);
    if (!(tid & 1)) {
        const int s = tid >> 1;               // 0..127
        #pragma unroll
        for (int j = 0; j < 16; ++j) tb[s * 17 + j] = p[j];
    }
    __syncthreads();
    {
        const int q = tid >> 4, g = tid & 15;
        float v = 0.f;
        #pragma unroll
        for (int j = 0; j < 8; ++j) v += tb[(g + 16 * j) * 17 + q];
        #pragma unroll
        for (int m = 1; m < 16; m <<= 1) v += __shfl_xor(v, m, 16);
        if (g == 0) dst[q] = v;
    }
    __syncthreads();
}

// ---------------------------------------------------------------------------
// k_rowdft: one (b,row) per block.
// R[b,row, 0..7]=Re, [8..15]=Im of sum_w x[b,0,row,w] e^{-2pi i ky w/512}
// ---------------------------------------------------------------------------
__global__ __launch_bounds__(256) void k_rowdft(const float* __restrict__ x,
                                                float* __restrict__ R) {
    __shared__ float tb[128 * 17];
    __shared__ float red[16];
    const int tid = threadIdx.x;
    const int b = blockIdx.x >> 9;
    const int row = blockIdx.x & 511;
    const float* xr = x + ((size_t)(b * NH + row)) * NW;
    const float xa = xr[tid], xb = xr[tid + 256];
    const float a = xa + xb, d = xa - xb;   // parity: tw(w+256)=(-1)^k tw(w)

    float p[16];
    float c1, s1;
    __sincosf(ANG512 * (float)tid, &s1, &c1);
    p[0] = a;      p[8] = 0.f;
    p[1] = d * c1; p[9] = -d * s1;
    {
        const float c2k = 2.f * c1;
        float ckm = 1.f, skm = 0.f, ck = c1, sk = s1;
        #pragma unroll
        for (int k = 2; k < 8; ++k) {
            const float cn = fmaf(c2k, ck, -ckm);
            const float sn = fmaf(c2k, sk, -skm);
            ckm = ck; skm = sk; ck = cn; sk = sn;
            const float v = (k & 1) ? d : a;
            p[k] = v * ck;
            p[8 + k] = -v * sk;
        }
    }
    treduce16(p, tb, red, tid);
    if (tid < 16) R[((size_t)(b * NH + row)) * 16 + tid] = red[tid];
}

// ---------------------------------------------------------------------------
// k_modes: grid (b,kx) = 64 blocks.
//  col-DFT of R -> X2d[ky]; X0 = fc0-fold; 3-layer mode recurrence;
//  AH[b,hd,ky,kx] = c_ky * sum_c fc1[c,hd] A[c,ky].
//  block 0 additionally computes gvec/Kvec.
// ---------------------------------------------------------------------------
__global__ __launch_bounds__(256) void k_modes(
        const float* __restrict__ R,
        const float* __restrict__ spec_wr, const float* __restrict__ spec_wi,
        const float* __restrict__ conv_w, const float* __restrict__ conv_b,
        const float* __restrict__ fc0_w, const float* __restrict__ fc0_b,
        const float* __restrict__ fc1_w, const float* __restrict__ fc1_b,
        float* __restrict__ AH, float* __restrict__ gvec, float* __restrict__ Kvec) {
    __shared__ float Wr_s[3][16][16][8];   // 24 KB
    __shared__ float Wi_s[3][16][16][8];   // 24 KB
    __shared__ float tb[128 * 17];
    __shared__ float X2[16];
    __shared__ float Xr[16][8], Xi[16][8];
    __shared__ float Fr[16][8], Fi[16][8];
    __shared__ float Ar[16][8], Ai[16][8];
    __shared__ float Pm[2][256];           // [0]=C2*C1, [1]=C2
    __shared__ float fc1_s[1024];
    __shared__ float ps[64];               // prep scratch (block 0)

    const int tid = threadIdx.x;
    const int bb = blockIdx.x >> 3;
    const int kx = blockIdx.x & 7;

    // ---- stage spectral weights for this kx ----
    {
        const int i = tid >> 4, o = tid & 15;
        #pragma unroll
        for (int d = 0; d < 3; ++d) {
            const size_t base = (size_t)d * SPEC_D + ((size_t)(i * 16 + o) * 64 + kx * 8);
            const float4* pr = (const float4*)(spec_wr + base);
            const float4* pi = (const float4*)(spec_wi + base);
            *(float4*)(&Wr_s[d][i][o][0]) = pr[0];
            *(float4*)(&Wr_s[d][i][o][4]) = pr[1];
            *(float4*)(&Wi_s[d][i][o][0]) = pi[0];
            *(float4*)(&Wi_s[d][i][o][4]) = pi[1];
        }
    }
    // ---- Pm[0] = C2*C1 (in-block), Pm[1] = C2, stage fc1 ----
    {
        const int o = tid >> 4, c = tid & 15;
        float s = 0.f;
        for (int k = 0; k < 16; ++k)
            s += conv_w[512 + o * 16 + k] * conv_w[256 + k * 16 + c];
        Pm[0][tid] = s;
    }
    Pm[1][tid] = conv_w[512 + tid];
    #pragma unroll
    for (int k = 0; k < 4; ++k) fc1_s[tid + k * 256] = fc1_w[tid + k * 256];

    // ---- col-DFT: X2d[ky] = sum_row R[bb,row,ky] e^{-2pi i kx row/512} ----
    float p[16];
    #pragma unroll
    for (int j = 0; j < 16; ++j) p[j] = 0.f;
    #pragma unroll
    for (int r2 = 0; r2 < 2; ++r2) {
        const int row = tid + r2 * 256;
        const float4* rp4 = (const float4*)(R + ((size_t)(bb * NH + row)) * 16);
        const float4 q0 = rp4[0], q1 = rp4[1], q2 = rp4[2], q3 = rp4[3];
        const float re[8] = {q0.x, q0.y, q0.z, q0.w, q1.x, q1.y, q1.z, q1.w};
        const float im[8] = {q2.x, q2.y, q2.z, q2.w, q3.x, q3.y, q3.z, q3.w};
        const int m = (kx * row) & 511;
        float cm, sm;
        __sincosf(ANG512 * (float)m, &sm, &cm);   // e^{-i th m} = (cm, -sm)
        #pragma unroll
        for (int k = 0; k < 8; ++k) {
            p[k]     += re[k] * cm + im[k] * sm;
            p[8 + k] += im[k] * cm - re[k] * sm;
        }
    }
    treduce16(p, tb, X2, tid);   // internal syncs also cover the staging above

    // ---- recurrence: thread = (o,ky), tid < 128 ----
    const bool act = (tid < 128);
    const int o = tid >> 3, ky = tid & 7;
    if (act) {
        const float inv = 1.f / (512.f * 512.f);
        float xr0 = fc0_w[o] * X2[ky] * inv;
        float xi0 = fc0_w[o] * X2[8 + ky] * inv;
        if (kx == 0 && ky == 0) xr0 += fc0_b[o];
        Xr[o][ky] = xr0; Xi[o][ky] = xi0;
        Ar[o][ky] = 0.f; Ai[o][ky] = 0.f;
    }
    __syncthreads();

    for (int dd = 0; dd < 3; ++dd) {
        if (act) {
            float fr = 0.f, fi = 0.f;
            #pragma unroll
            for (int i = 0; i < 16; ++i) {
                const float wre = Wr_s[dd][i][o][ky];
                const float wim = Wi_s[dd][i][o][ky];
                const float xr0 = Xr[i][ky], xi0 = Xi[i][ky];
                fr += xr0 * wre - xi0 * wim;
                fi += xr0 * wim + xi0 * wre;
            }
            Fr[o][ky] = fr; Fi[o][ky] = fi;
        }
        __syncthreads();
        float xnr = 0.f, xni = 0.f;
        if (act) {
            float ar, ai;
            if (dd == 2) {
                ar = Fr[o][ky]; ai = Fi[o][ky];
            } else {
                ar = 0.f; ai = 0.f;
                #pragma unroll
                for (int c = 0; c < 16; ++c) {
                    const float pv = Pm[dd][o * 16 + c];
                    ar = fmaf(pv, Fr[c][ky], ar);
                    ai = fmaf(pv, Fi[c][ky], ai);
                }
            }
            Ar[o][ky] += ar; Ai[o][ky] += ai;
            if (dd < 2) {
                const float fr0 = Fr[o][ky], fi0 = Fi[o][ky];
                if (ky == 0) {
                    if (kx == 0) { xnr = fr0; xni = 0.f; }
                    else         { xnr = 0.5f * fr0; xni = 0.5f * fi0; }
                } else { xnr = fr0; xni = fi0; }
                #pragma unroll
                for (int c = 0; c < 16; ++c) {
                    const float cc = conv_w[dd * 256 + o * 16 + c];
                    xnr = fmaf(cc, Xr[c][ky], xnr);
                    xni = fmaf(cc, Xi[c][ky], xni);
                }
                if (kx == 0 && ky == 0) xnr += conv_b[dd * 16 + o];
            }
        }
        __syncthreads();
        if (act && dd < 2) { Xr[o][ky] = xnr; Xi[o][ky] = xni; }
        __syncthreads();
    }

    // ---- fold fc1 -> AH[b,hd,ky,kx] (interleaved complex) ----
    #pragma unroll
    for (int k2 = 0; k2 < 2; ++k2) {
        const int idx = tid + k2 * 256;      // hd*8 + ky2
        const int hd = idx >> 3, ky2 = idx & 7;
        float ar = 0.f, ai = 0.f;
        #pragma unroll
        for (int c = 0; c < 16; ++c) {
            const float f = fc1_s[c * 64 + hd];
            ar = fmaf(f, Ar[c][ky2], ar);
            ai = fmaf(f, Ai[c][ky2], ai);
        }
        const float ck = (ky2 == 0) ? 1.f : 2.f;    // Hermitian doubling
        const size_t off = ((((size_t)(bb * 64 + hd)) * 8 + ky2) * 8 + kx) * 2;
        AH[off] = ck * ar;
        AH[off + 1] = ck * ai;
    }

    // ---- block 0: gvec = fc1^T(P0*C0*fc0_w); Kvec = fc1_b + fc1^T(evec) ----
    if (blockIdx.x == 0) {
        if (tid < 16) {
            float su = 0.f, sb = 0.f;
            for (int c = 0; c < 16; ++c) {
                su += conv_w[tid * 16 + c] * fc0_w[c];
                sb += conv_w[tid * 16 + c] * fc0_b[c];
            }
            ps[tid] = su; ps[16 + tid] = sb;
        }
        __syncthreads();
        if (tid < 16) {
            float dv = 0.f, ev = conv_b[32 + tid];
            for (int k = 0; k < 16; ++k) {
                dv += Pm[0][tid * 16 + k] * ps[k];
                ev += Pm[0][tid * 16 + k] * (ps[16 + k] + conv_b[k]);
                ev += conv_w[512 + tid * 16 + k] * conv_b[16 + k];
            }
            ps[32 + tid] = dv; ps[48 + tid] = ev;
        }
        __syncthreads();
        if (tid < 64) {
            float g = 0.f, K = fc1_b[tid];
            for (int c = 0; c < 16; ++c) {
                g = fmaf(fc1_w[c * 64 + tid], ps[32 + c], g);
                K = fmaf(fc1_w[c * 64 + tid], ps[48 + c], K);
            }
            gvec[tid] = g; Kvec[tid] = K;
        }
    }
}

// ---------------------------------------------------------------------------
// k_head: 2 rows per block, 4 px/thread via i^ky quarter-rotation.
// WH[hd,ky] = sum_kx AH e^{+i kx th_row}  (Kvec folded into ky=0 real)
// s_hd(w)   = Re sum_ky WH e^{+i ky th_w} + gvec[hd]*x
// out = fc2_b + sum_hd relu(s_hd) * fc2_w[hd]
// __launch_bounds__(256,8): VGPR<=64 (already achieved at (256,4)) -> 8 blk/CU
// so the ds_read_b128 stream runs at throughput, not latency.
// ---------------------------------------------------------------------------
__global__ __launch_bounds__(256, 8) void k_head(
        const float* __restrict__ x, const float* __restrict__ AH,
        const float* __restrict__ gvec, const float* __restrict__ Kvec,
        const float* __restrict__ fc2_w, const float* __restrict__ fc2_b,
        float* __restrict__ out) {
    __shared__ float WHr[2][512];
    __shared__ float WHi[2][512];

    const int tid = threadIdx.x;
    const int b = blockIdx.x >> 8;
    const int rp = blockIdx.x & 255;
    const int half = tid >> 7;
    const int row = rp * 2 + half;
    const int t7 = tid & 127;

    // hoist x loads: overlap global latency with the WH build
    const int w0 = t7;
    const float* xp = x + ((size_t)(b * NH + row)) * NW + w0;
    const float x0 = xp[0], x1 = xp[128], x2 = xp[256], x3 = xp[384];

    // ---- WH build (4 entries/thread for this thread's row) ----
    {
        float c1, s1;
        __sincosf(ANG512 * (float)row, &s1, &c1);
        float ctr[8], str[8];
        ctr[0] = 1.f; str[0] = 0.f; ctr[1] = c1; str[1] = s1;
        const float c2k = 2.f * c1;
        #pragma unroll
        for (int k = 2; k < 8; ++k) {
            ctr[k] = fmaf(c2k, ctr[k - 1], -ctr[k - 2]);
            str[k] = fmaf(c2k, str[k - 1], -str[k - 2]);
        }
        #pragma unroll
        for (int k2 = 0; k2 < 4; ++k2) {
            const int idx = t7 + k2 * 128;   // hd*8 + ky
            const int hd = idx >> 3, ky = idx & 7;
            const float4* ap = (const float4*)(AH + ((size_t)(b * 64 + hd) * 8 + ky) * 16);
            const float4 a0 = ap[0], a1 = ap[1], a2 = ap[2], a3 = ap[3];
            float wr = a0.x, wi = a0.y;      // kx=0
            wr = fmaf(a0.z, ctr[1], wr); wr = fmaf(-a0.w, str[1], wr);
            wi = fmaf(a0.z, str[1], wi); wi = fmaf(a0.w, ctr[1], wi);
            wr = fmaf(a1.x, ctr[2], wr); wr = fmaf(-a1.y, str[2], wr);
            wi = fmaf(a1.x, str[2], wi); wi = fmaf(a1.y, ctr[2], wi);
            wr = fmaf(a1.z, ctr[3], wr); wr = fmaf(-a1.w, str[3], wr);
            wi = fmaf(a1.z, str[3], wi); wi = fmaf(a1.w, ctr[3], wi);
            wr = fmaf(a2.x, ctr[4], wr); wr = fmaf(-a2.y, str[4], wr);
            wi = fmaf(a2.x, str[4], wi); wi = fmaf(a2.y, ctr[4], wi);
            wr = fmaf(a2.z, ctr[5], wr); wr = fmaf(-a2.w, str[5], wr);
            wi = fmaf(a2.z, str[5], wi); wi = fmaf(a2.w, ctr[5], wi);
            wr = fmaf(a3.x, ctr[6], wr); wr = fmaf(-a3.y, str[6], wr);
            wi = fmaf(a3.x, str[6], wi); wi = fmaf(a3.y, ctr[6], wi);
            wr = fmaf(a3.z, ctr[7], wr); wr = fmaf(-a3.w, str[7], wr);
            wi = fmaf(a3.z, str[7], wi); wi = fmaf(a3.w, ctr[7], wi);
            if (ky == 0) wr += Kvec[hd];
            WHr[half][idx] = wr;
            WHi[half][idx] = wi;
        }
    }
    __syncthreads();

    // ---- 4 px/thread: w0, w0+128, w0+256, w0+384 (i^ky rotation) ----
    {
        float c1, s1;
        __sincosf(ANG512 * (float)w0, &s1, &c1);
        float ct[8], st[8];
        ct[0] = 1.f; st[0] = 0.f; ct[1] = c1; st[1] = s1;
        const float c2k = 2.f * c1;
        #pragma unroll
        for (int k = 2; k < 8; ++k) {
            ct[k] = fmaf(c2k, ct[k - 1], -ct[k - 2]);
            st[k] = fmaf(c2k, st[k - 1], -st[k - 2]);
        }
        const float* WR = &WHr[half][0];
        const float* WI = &WHi[half][0];
        const float fc2b = fc2_b[0];
        float acc0 = fc2b, acc1 = fc2b, acc2 = fc2b, acc3 = fc2b;
        #pragma unroll 4
        for (int hd = 0; hd < 64; ++hd) {
            const float4* r4 = (const float4*)(WR + hd * 8);
            const float4 wa = r4[0], wb = r4[1];
            const float4* i4 = (const float4*)(WI + hd * 8);
            const float4 va = i4[0], vb = i4[1];
            const float tr0 = wa.x;
            const float tr1 = wa.y * ct[1] - va.y * st[1];
            const float tr2 = wa.z * ct[2] - va.z * st[2];
            const float tr3 = wa.w * ct[3] - va.w * st[3];
            const float tr4 = wb.x * ct[4] - vb.x * st[4];
            const float tr5 = wb.y * ct[5] - vb.y * st[5];
            const float tr6 = wb.z * ct[6] - vb.z * st[6];
            const float tr7 = wb.w * ct[7] - vb.w * st[7];
            const float ti1 = wa.y * st[1] + va.y * ct[1];
            const float ti3 = wa.w * st[3] + va.w * ct[3];
            const float ti5 = wb.y * st[5] + vb.y * ct[5];
            const float ti7 = wb.w * st[7] + vb.w * ct[7];
            const float A0 = tr0 + tr4, A2 = tr2 + tr6;
            const float B13 = (tr1 + tr5) + (tr3 + tr7);
            const float U = (ti1 + ti5) - (ti3 + ti7);
            const float E = A0 + A2, D = A0 - A2;
            const float gh = gvec[hd];
            const float w2 = fc2_w[hd];
            const float s0 = E + B13 + gh * x0;
            const float s1p = D - U + gh * x1;
            const float s2p = E - B13 + gh * x2;
            const float s3p = D + U + gh * x3;
            acc0 = fmaf(fmaxf(s0, 0.f),  w2, acc0);
            acc1 = fmaf(fmaxf(s1p, 0.f), w2, acc1);
            acc2 = fmaf(fmaxf(s2p, 0.f), w2, acc2);
            acc3 = fmaf(fmaxf(s3p, 0.f), w2, acc3);
        }
        float* op = out + ((size_t)(b * NH + row)) * NW + w0;
        op[0] = acc0; op[128] = acc1; op[256] = acc2; op[384] = acc3;
    }
}

// ---------------------------------------------------------------------------
extern "C" void kernel_launch(void* const* d_in, const int* in_sizes, int n_in,
                              void* d_out, int out_size, void* d_ws, size_t ws_size,
                              hipStream_t stream) {
    const float* x       = (const float*)d_in[0];
    const float* fc0_w   = (const float*)d_in[1];
    const float* fc0_b   = (const float*)d_in[2];
    const float* spec_wr = (const float*)d_in[3];
    const float* spec_wi = (const float*)d_in[4];
    const float* conv_w  = (const float*)d_in[5];
    const float* conv_b  = (const float*)d_in[6];
    const float* fc1_w   = (const float*)d_in[7];
    const float* fc1_b   = (const float*)d_in[8];
    const float* fc2_w   = (const float*)d_in[9];
    const float* fc2_b   = (const float*)d_in[10];
    float* outp = (float*)d_out;

    char* ws = (char*)d_ws;
    float* R  = (float*)ws;                       // 8*512*16 floats = 256 KB
    float* AH = (float*)(ws + 262144);            // 8*64*64*2 floats = 256 KB
    float* gv = (float*)(ws + 524288);            // 64 floats
    float* Kv = (float*)(ws + 524288 + 256);      // 64 floats

    k_rowdft<<<NB * NH, 256, 0, stream>>>(x, R);
    k_modes<<<NB * 8, 256, 0, stream>>>(R, spec_wr, spec_wi, conv_w, conv_b,
                                        fc0_w, fc0_b, fc1_w, fc1_b, AH, gv, Kv);
    k_head<<<NB * 256, 256, 0, stream>>>(x, AH, gv, Kv, fc2_w, fc2_b, outp);
}

// Round 10
// 144.742 us; speedup vs baseline: 2.9087x; 1.0053x over previous
//
#include <hip/hip_runtime.h>
#include <math.h>

#define NB 8
#define NH 512
#define NW 512
#define ANG512 0.01227184630308513f
#define SPEC_D 16384   // per-depth stride of spec_wr/spec_wi (16*16*8*8)

// ---------------------------------------------------------------------------
// transpose-reduce: 256 threads each hold p[16]; result (sum over threads)
// lands in dst[0..15]. tb must hold 128*17 floats.
// ---------------------------------------------------------------------------
__device__ __forceinline__ void treduce16(float* p, float* tb, float* dst, int tid) {
    #pragma unroll
    for (int j = 0; j < 16; ++j) p[j] += __shfl_xor(p[j], 1);
    if (!(tid & 1)) {
        const int s = tid >> 1;               // 0..127
        #pragma unroll
        for (int j = 0; j < 16; ++j) tb[s * 17 + j] = p[j];
    }
    __syncthreads();
    {
        const int q = tid >> 4, g = tid & 15;
        float v = 0.f;
        #pragma unroll
        for (int j = 0; j < 8; ++j) v += tb[(g + 16 * j) * 17 + q];
        #pragma unroll
        for (int m = 1; m < 16; m <<= 1) v += __shfl_xor(v, m, 16);
        if (g == 0) dst[q] = v;
    }
    __syncthreads();
}

// ---------------------------------------------------------------------------
// k_rowdft: one (b,row) per block.
// R[b,row, 0..7]=Re, [8..15]=Im of sum_w x[b,0,row,w] e^{-2pi i ky w/512}
// ---------------------------------------------------------------------------
__global__ __launch_bounds__(256) void k_rowdft(const float* __restrict__ x,
                                                float* __restrict__ R) {
    __shared__ float tb[128 * 17];
    __shared__ float red[16];
    const int tid = threadIdx.x;
    const int b = blockIdx.x >> 9;
    const int row = blockIdx.x & 511;
    const float* xr = x + ((size_t)(b * NH + row)) * NW;
    const float xa = xr[tid], xb = xr[tid + 256];
    const float a = xa + xb, d = xa - xb;   // parity: tw(w+256)=(-1)^k tw(w)

    float p[16];
    float c1, s1;
    __sincosf(ANG512 * (float)tid, &s1, &c1);
    p[0] = a;      p[8] = 0.f;
    p[1] = d * c1; p[9] = -d * s1;
    {
        const float c2k = 2.f * c1;
        float ckm = 1.f, skm = 0.f, ck = c1, sk = s1;
        #pragma unroll
        for (int k = 2; k < 8; ++k) {
            const float cn = fmaf(c2k, ck, -ckm);
            const float sn = fmaf(c2k, sk, -skm);
            ckm = ck; skm = sk; ck = cn; sk = sn;
            const float v = (k & 1) ? d : a;
            p[k] = v * ck;
            p[8 + k] = -v * sk;
        }
    }
    treduce16(p, tb, red, tid);
    if (tid < 16) R[((size_t)(b * NH + row)) * 16 + tid] = red[tid];
}

// ---------------------------------------------------------------------------
// k_modes: grid (b,kx) = 64 blocks.
//  col-DFT of R -> X2d[ky]; X0 = fc0-fold; 3-layer mode recurrence;
//  AH[b,hd,ky,kx] = c_ky * sum_c fc1[c,hd] A[c,ky].
//  block 0 additionally computes gvec/Kvec.
// ---------------------------------------------------------------------------
__global__ __launch_bounds__(256) void k_modes(
        const float* __restrict__ R,
        const float* __restrict__ spec_wr, const float* __restrict__ spec_wi,
        const float* __restrict__ conv_w, const float* __restrict__ conv_b,
        const float* __restrict__ fc0_w, const float* __restrict__ fc0_b,
        const float* __restrict__ fc1_w, const float* __restrict__ fc1_b,
        float* __restrict__ AH, float* __restrict__ gvec, float* __restrict__ Kvec) {
    __shared__ float Wr_s[3][16][16][8];   // 24 KB
    __shared__ float Wi_s[3][16][16][8];   // 24 KB
    __shared__ float tb[128 * 17];
    __shared__ float X2[16];
    __shared__ float Xr[16][8], Xi[16][8];
    __shared__ float Fr[16][8], Fi[16][8];
    __shared__ float Ar[16][8], Ai[16][8];
    __shared__ float Pm[2][256];           // [0]=C2*C1, [1]=C2
    __shared__ float fc1_s[1024];
    __shared__ float ps[64];               // prep scratch (block 0)

    const int tid = threadIdx.x;
    const int bb = blockIdx.x >> 3;
    const int kx = blockIdx.x & 7;

    // ---- stage spectral weights for this kx ----
    {
        const int i = tid >> 4, o = tid & 15;
        #pragma unroll
        for (int d = 0; d < 3; ++d) {
            const size_t base = (size_t)d * SPEC_D + ((size_t)(i * 16 + o) * 64 + kx * 8);
            const float4* pr = (const float4*)(spec_wr + base);
            const float4* pi = (const float4*)(spec_wi + base);
            *(float4*)(&Wr_s[d][i][o][0]) = pr[0];
            *(float4*)(&Wr_s[d][i][o][4]) = pr[1];
            *(float4*)(&Wi_s[d][i][o][0]) = pi[0];
            *(float4*)(&Wi_s[d][i][o][4]) = pi[1];
        }
    }
    // ---- Pm[0] = C2*C1 (in-block), Pm[1] = C2, stage fc1 ----
    {
        const int o = tid >> 4, c = tid & 15;
        float s = 0.f;
        for (int k = 0; k < 16; ++k)
            s += conv_w[512 + o * 16 + k] * conv_w[256 + k * 16 + c];
        Pm[0][tid] = s;
    }
    Pm[1][tid] = conv_w[512 + tid];
    #pragma unroll
    for (int k = 0; k < 4; ++k) fc1_s[tid + k * 256] = fc1_w[tid + k * 256];

    // ---- col-DFT: X2d[ky] = sum_row R[bb,row,ky] e^{-2pi i kx row/512} ----
    float p[16];
    #pragma unroll
    for (int j = 0; j < 16; ++j) p[j] = 0.f;
    #pragma unroll
    for (int r2 = 0; r2 < 2; ++r2) {
        const int row = tid + r2 * 256;
        const float4* rp4 = (const float4*)(R + ((size_t)(bb * NH + row)) * 16);
        const float4 q0 = rp4[0], q1 = rp4[1], q2 = rp4[2], q3 = rp4[3];
        const float re[8] = {q0.x, q0.y, q0.z, q0.w, q1.x, q1.y, q1.z, q1.w};
        const float im[8] = {q2.x, q2.y, q2.z, q2.w, q3.x, q3.y, q3.z, q3.w};
        const int m = (kx * row) & 511;
        float cm, sm;
        __sincosf(ANG512 * (float)m, &sm, &cm);   // e^{-i th m} = (cm, -sm)
        #pragma unroll
        for (int k = 0; k < 8; ++k) {
            p[k]     += re[k] * cm + im[k] * sm;
            p[8 + k] += im[k] * cm - re[k] * sm;
        }
    }
    treduce16(p, tb, X2, tid);   // internal syncs also cover the staging above

    // ---- recurrence: thread = (o,ky), tid < 128 ----
    const bool act = (tid < 128);
    const int o = tid >> 3, ky = tid & 7;
    if (act) {
        const float inv = 1.f / (512.f * 512.f);
        float xr0 = fc0_w[o] * X2[ky] * inv;
        float xi0 = fc0_w[o] * X2[8 + ky] * inv;
        if (kx == 0 && ky == 0) xr0 += fc0_b[o];
        Xr[o][ky] = xr0; Xi[o][ky] = xi0;
        Ar[o][ky] = 0.f; Ai[o][ky] = 0.f;
    }
    __syncthreads();

    for (int dd = 0; dd < 3; ++dd) {
        if (act) {
            float fr = 0.f, fi = 0.f;
            #pragma unroll
            for (int i = 0; i < 16; ++i) {
                const float wre = Wr_s[dd][i][o][ky];
                const float wim = Wi_s[dd][i][o][ky];
                const float xr0 = Xr[i][ky], xi0 = Xi[i][ky];
                fr += xr0 * wre - xi0 * wim;
                fi += xr0 * wim + xi0 * wre;
            }
            Fr[o][ky] = fr; Fi[o][ky] = fi;
        }
        __syncthreads();
        float xnr = 0.f, xni = 0.f;
        if (act) {
            float ar, ai;
            if (dd == 2) {
                ar = Fr[o][ky]; ai = Fi[o][ky];
            } else {
                ar = 0.f; ai = 0.f;
                #pragma unroll
                for (int c = 0; c < 16; ++c) {
                    const float pv = Pm[dd][o * 16 + c];
                    ar = fmaf(pv, Fr[c][ky], ar);
                    ai = fmaf(pv, Fi[c][ky], ai);
                }
            }
            Ar[o][ky] += ar; Ai[o][ky] += ai;
            if (dd < 2) {
                const float fr0 = Fr[o][ky], fi0 = Fi[o][ky];
                if (ky == 0) {
                    if (kx == 0) { xnr = fr0; xni = 0.f; }
                    else         { xnr = 0.5f * fr0; xni = 0.5f * fi0; }
                } else { xnr = fr0; xni = fi0; }
                #pragma unroll
                for (int c = 0; c < 16; ++c) {
                    const float cc = conv_w[dd * 256 + o * 16 + c];
                    xnr = fmaf(cc, Xr[c][ky], xnr);
                    xni = fmaf(cc, Xi[c][ky], xni);
                }
                if (kx == 0 && ky == 0) xnr += conv_b[dd * 16 + o];
            }
        }
        __syncthreads();
        if (act && dd < 2) { Xr[o][ky] = xnr; Xi[o][ky] = xni; }
        __syncthreads();
    }

    // ---- fold fc1 -> AH[b,hd,ky,kx] (interleaved complex) ----
    #pragma unroll
    for (int k2 = 0; k2 < 2; ++k2) {
        const int idx = tid + k2 * 256;      // hd*8 + ky2
        const int hd = idx >> 3, ky2 = idx & 7;
        float ar = 0.f, ai = 0.f;
        #pragma unroll
        for (int c = 0; c < 16; ++c) {
            const float f = fc1_s[c * 64 + hd];
            ar = fmaf(f, Ar[c][ky2], ar);
            ai = fmaf(f, Ai[c][ky2], ai);
        }
        const float ck = (ky2 == 0) ? 1.f : 2.f;    // Hermitian doubling
        const size_t off = ((((size_t)(bb * 64 + hd)) * 8 + ky2) * 8 + kx) * 2;
        AH[off] = ck * ar;
        AH[off + 1] = ck * ai;
    }

    // ---- block 0: gvec = fc1^T(P0*C0*fc0_w); Kvec = fc1_b + fc1^T(evec) ----
    if (blockIdx.x == 0) {
        if (tid < 16) {
            float su = 0.f, sb = 0.f;
            for (int c = 0; c < 16; ++c) {
                su += conv_w[tid * 16 + c] * fc0_w[c];
                sb += conv_w[tid * 16 + c] * fc0_b[c];
            }
            ps[tid] = su; ps[16 + tid] = sb;
        }
        __syncthreads();
        if (tid < 16) {
            float dv = 0.f, ev = conv_b[32 + tid];
            for (int k = 0; k < 16; ++k) {
                dv += Pm[0][tid * 16 + k] * ps[k];
                ev += Pm[0][tid * 16 + k] * (ps[16 + k] + conv_b[k]);
                ev += conv_w[512 + tid * 16 + k] * conv_b[16 + k];
            }
            ps[32 + tid] = dv; ps[48 + tid] = ev;
        }
        __syncthreads();
        if (tid < 64) {
            float g = 0.f, K = fc1_b[tid];
            for (int c = 0; c < 16; ++c) {
                g = fmaf(fc1_w[c * 64 + tid], ps[32 + c], g);
                K = fmaf(fc1_w[c * 64 + tid], ps[48 + c], K);
            }
            gvec[tid] = g; Kvec[tid] = K;
        }
    }
}

// ---------------------------------------------------------------------------
// k_head: 4 rows/block (wave = row), 8 px/thread.
// One WH read serves 8 pixels: quad {w0+128m} via i^ky rotation, and the
// shifted quad {w0+64+128m} via the compile-time e^{i ky pi/4} rotation of
// the SAME tr/ti values. LDS instr/px halved vs 4px version.
// 1024 blocks = 4/CU co-resident; (256,4) -> 128 VGPR budget, no remat.
// ---------------------------------------------------------------------------
__global__ __launch_bounds__(256, 4) void k_head(
        const float* __restrict__ x, const float* __restrict__ AH,
        const float* __restrict__ gvec, const float* __restrict__ Kvec,
        const float* __restrict__ fc2_w, const float* __restrict__ fc2_b,
        float* __restrict__ out) {
    __shared__ float WHr[4][512];
    __shared__ float WHi[4][512];

    const int tid = threadIdx.x;
    const int b = blockIdx.x >> 7;       // 1024 blocks total
    const int rp = blockIdx.x & 127;     // group of 4 rows
    const int rl = tid >> 6;             // wave index = local row
    const int row = rp * 4 + rl;
    const int w0 = tid & 63;

    // hoist x loads (coalesced, latency overlapped with WH build)
    const float* xp = x + ((size_t)(b * NH + row)) * NW + w0;
    float xv[8];
    #pragma unroll
    for (int j = 0; j < 8; ++j) xv[j] = xp[j * 64];

    // ---- WH build: 8 entries/thread for this wave's row ----
    {
        float c1, s1;
        __sincosf(ANG512 * (float)row, &s1, &c1);
        float ctr[8], str[8];
        ctr[0] = 1.f; str[0] = 0.f; ctr[1] = c1; str[1] = s1;
        const float c2k = 2.f * c1;
        #pragma unroll
        for (int k = 2; k < 8; ++k) {
            ctr[k] = fmaf(c2k, ctr[k - 1], -ctr[k - 2]);
            str[k] = fmaf(c2k, str[k - 1], -str[k - 2]);
        }
        #pragma unroll
        for (int j = 0; j < 8; ++j) {
            const int idx = w0 + j * 64;     // hd*8 + ky
            const int hd = idx >> 3, ky = idx & 7;
            const float4* ap = (const float4*)(AH + ((size_t)(b * 64 + hd) * 8 + ky) * 16);
            const float4 a0 = ap[0], a1 = ap[1], a2 = ap[2], a3 = ap[3];
            float wr = a0.x, wi = a0.y;      // kx=0
            wr = fmaf(a0.z, ctr[1], wr); wr = fmaf(-a0.w, str[1], wr);
            wi = fmaf(a0.z, str[1], wi); wi = fmaf(a0.w, ctr[1], wi);
            wr = fmaf(a1.x, ctr[2], wr); wr = fmaf(-a1.y, str[2], wr);
            wi = fmaf(a1.x, str[2], wi); wi = fmaf(a1.y, ctr[2], wi);
            wr = fmaf(a1.z, ctr[3], wr); wr = fmaf(-a1.w, str[3], wr);
            wi = fmaf(a1.z, str[3], wi); wi = fmaf(a1.w, ctr[3], wi);
            wr = fmaf(a2.x, ctr[4], wr); wr = fmaf(-a2.y, str[4], wr);
            wi = fmaf(a2.x, str[4], wi); wi = fmaf(a2.y, ctr[4], wi);
            wr = fmaf(a2.z, ctr[5], wr); wr = fmaf(-a2.w, str[5], wr);
            wi = fmaf(a2.z, str[5], wi); wi = fmaf(a2.w, ctr[5], wi);
            wr = fmaf(a3.x, ctr[6], wr); wr = fmaf(-a3.y, str[6], wr);
            wi = fmaf(a3.x, str[6], wi); wi = fmaf(a3.y, ctr[6], wi);
            wr = fmaf(a3.z, ctr[7], wr); wr = fmaf(-a3.w, str[7], wr);
            wi = fmaf(a3.z, str[7], wi); wi = fmaf(a3.w, ctr[7], wi);
            if (ky == 0) wr += Kvec[hd];
            WHr[rl][idx] = wr;
            WHi[rl][idx] = wi;
        }
    }
    __syncthreads();

    // ---- 8 px/thread: w0 + 64*j ----
    {
        float c1, s1;
        __sincosf(ANG512 * (float)w0, &s1, &c1);
        float ct[8], st[8];
        ct[0] = 1.f; st[0] = 0.f; ct[1] = c1; st[1] = s1;
        const float c2k = 2.f * c1;
        #pragma unroll
        for (int k = 2; k < 8; ++k) {
            ct[k] = fmaf(c2k, ct[k - 1], -ct[k - 2]);
            st[k] = fmaf(c2k, st[k - 1], -st[k - 2]);
        }
        const float r2c = 0.70710678118654752f;
        const float* WR = &WHr[rl][0];
        const float* WI = &WHi[rl][0];
        const float fc2b = fc2_b[0];
        float acc[8];
        #pragma unroll
        for (int j = 0; j < 8; ++j) acc[j] = fc2b;

        #pragma unroll 4
        for (int hd = 0; hd < 64; ++hd) {
            const float4* r4 = (const float4*)(WR + hd * 8);
            const float4 wa = r4[0], wb = r4[1];
            const float4* i4 = (const float4*)(WI + hd * 8);
            const float4 va = i4[0], vb = i4[1];
            // tr_k = Re[WH_k e^{ik th}], ti_k = Im[...]
            const float tr0 = wa.x;
            const float tr1 = wa.y * ct[1] - va.y * st[1];
            const float ti1 = wa.y * st[1] + va.y * ct[1];
            const float tr2 = wa.z * ct[2] - va.z * st[2];
            const float ti2 = wa.z * st[2] + va.z * ct[2];
            const float tr3 = wa.w * ct[3] - va.w * st[3];
            const float ti3 = wa.w * st[3] + va.w * ct[3];
            const float tr4 = wb.x * ct[4] - vb.x * st[4];
            const float tr5 = wb.y * ct[5] - vb.y * st[5];
            const float ti5 = wb.y * st[5] + vb.y * ct[5];
            const float tr6 = wb.z * ct[6] - vb.z * st[6];
            const float ti6 = wb.z * st[6] + vb.z * ct[6];
            const float tr7 = wb.w * ct[7] - vb.w * st[7];
            const float ti7 = wb.w * st[7] + vb.w * ct[7];

            const float gh = gvec[hd];
            const float w2 = fc2_w[hd];

            // quad 1: pixels w0 + 128m  (i^ky rotation)
            const float A0 = tr0 + tr4, A2 = tr2 + tr6;
            const float E = A0 + A2, D = A0 - A2;
            const float B13 = (tr1 + tr5) + (tr3 + tr7);
            const float U = (ti1 + ti5) - (ti3 + ti7);
            const float s0 = fmaf(gh, xv[0], E + B13);
            const float s2 = fmaf(gh, xv[2], D - U);
            const float s4 = fmaf(gh, xv[4], E - B13);
            const float s6 = fmaf(gh, xv[6], D + U);
            acc[0] = fmaf(fmaxf(s0, 0.f), w2, acc[0]);
            acc[2] = fmaf(fmaxf(s2, 0.f), w2, acc[2]);
            acc[4] = fmaf(fmaxf(s4, 0.f), w2, acc[4]);
            acc[6] = fmaf(fmaxf(s6, 0.f), w2, acc[6]);

            // quad 2: pixels w0+64+128m  (extra e^{i ky pi/4} rotation)
            const float P = tr0 - tr4, Q = ti6 - ti2;
            const float E2 = P + Q, D2 = P - Q;
            const float B2 = r2c * (((tr1 - ti1) - (tr5 - ti5)) + ((tr7 + ti7) - (tr3 + ti3)));
            const float U2 = r2c * (((tr1 + ti1) - (tr5 + ti5)) - ((tr3 - ti3) + (ti7 - tr7)));
            const float s1p = fmaf(gh, xv[1], E2 + B2);
            const float s3p = fmaf(gh, xv[3], D2 - U2);
            const float s5p = fmaf(gh, xv[5], E2 - B2);
            const float s7p = fmaf(gh, xv[7], D2 + U2);
            acc[1] = fmaf(fmaxf(s1p, 0.f), w2, acc[1]);
            acc[3] = fmaf(fmaxf(s3p, 0.f), w2, acc[3]);
            acc[5] = fmaf(fmaxf(s5p, 0.f), w2, acc[5]);
            acc[7] = fmaf(fmaxf(s7p, 0.f), w2, acc[7]);
        }
        float* op = out + ((size_t)(b * NH + row)) * NW + w0;
        #pragma unroll
        for (int j = 0; j < 8; ++j) op[j * 64] = acc[j];
    }
}

// ---------------------------------------------------------------------------
extern "C" void kernel_launch(void* const* d_in, const int* in_sizes, int n_in,
                              void* d_out, int out_size, void* d_ws, size_t ws_size,
                              hipStream_t stream) {
    const float* x       = (const float*)d_in[0];
    const float* fc0_w   = (const float*)d_in[1];
    const float* fc0_b   = (const float*)d_in[2];
    const float* spec_wr = (const float*)d_in[3];
    const float* spec_wi = (const float*)d_in[4];
    const float* conv_w  = (const float*)d_in[5];
    const float* conv_b  = (const float*)d_in[6];
    const float* fc1_w   = (const float*)d_in[7];
    const float* fc1_b   = (const float*)d_in[8];
    const float* fc2_w   = (const float*)d_in[9];
    const float* fc2_b   = (const float*)d_in[10];
    float* outp = (float*)d_out;

    char* ws = (char*)d_ws;
    float* R  = (float*)ws;                       // 8*512*16 floats = 256 KB
    float* AH = (float*)(ws + 262144);            // 8*64*64*2 floats = 256 KB
    float* gv = (float*)(ws + 524288);            // 64 floats
    float* Kv = (float*)(ws + 524288 + 256);      // 64 floats

    k_rowdft<<<NB * NH, 256, 0, stream>>>(x, R);
    k_modes<<<NB * 8, 256, 0, stream>>>(R, spec_wr, spec_wi, conv_w, conv_b,
                                        fc0_w, fc0_b, fc1_w, fc1_b, AH, gv, Kv);
    k_head<<<NB * 128, 256, 0, stream>>>(x, AH, gv, Kv, fc2_w, fc2_b, outp);
}